// Round 5
// baseline (402.265 us; speedup 1.0000x reference)
//
#include <hip/hip_runtime.h>
#include <hip/hip_fp16.h>
#include <math.h>

#define NROWS 8192
#define DDIM 384
#define HDIM 256
#define CDIM 6
#define LN_EPS 1e-5f

typedef short bf16x8 __attribute__((ext_vector_type(8)));
typedef float f32x4 __attribute__((ext_vector_type(4)));
typedef _Float16 f16x8 __attribute__((ext_vector_type(8)));
typedef _Float16 f16x4 __attribute__((ext_vector_type(4)));
typedef _Float16 f16x2 __attribute__((ext_vector_type(2)));

__device__ __forceinline__ bool dj_better(float d1, int j1, float d2, int j2) {
    return (d1 < d2) || (d1 == d2 && j1 < j2);
}

// ---------------- x (fp32) -> bf16 bits, round-to-nearest-even ----------------
__global__ void __launch_bounds__(256) tobf16_kernel(
    const float* __restrict__ x, unsigned short* __restrict__ xb)
{
    int i = blockIdx.x * 256 + threadIdx.x;
    unsigned int u = __float_as_uint(x[i]);
    u += 0x7fffu + ((u >> 16) & 1u);
    xb[i] = (unsigned short)(u >> 16);
}

// ---------------- sq[i] = ||x_i||^2, k[i] from tau ----------------
__global__ void __launch_bounds__(256) precompute_kernel(
    const float* __restrict__ x, const float* __restrict__ W_tau,
    const float* __restrict__ b_tau, float* __restrict__ sq, int* __restrict__ kk)
{
    int tid = threadIdx.x;
    int wave = tid >> 6, lane = tid & 63;
    int row = blockIdx.x * 4 + wave;
    const float* xr = x + (size_t)row * DDIM;
    float s = 0.f, tp = 0.f;
    #pragma unroll
    for (int q = 0; q < 6; ++q) {
        float v = xr[lane + 64 * q];
        s = fmaf(v, v, s);
        tp = fmaf(v, W_tau[lane + 64 * q], tp);
    }
    #pragma unroll
    for (int off = 32; off > 0; off >>= 1) {
        s += __shfl_xor(s, off);
        tp += __shfl_xor(tp, off);
    }
    if (lane == 0) {
        sq[row] = s;
        float u = tp + b_tau[0];
        float tau = 1.f / (1.f + expf(-u));
        float kf = rintf(16.f - 12.f * tau);
        int k = (int)kf;
        k = min(16, max(1, k));
        kk[row] = k;
    }
}

// ---------------- fp32 tiled GEMM: out = relu(A[M,K] @ W[K,N] + bias) ----------------
__global__ void __launch_bounds__(256) gemm_bias_relu_kernel(
    const float* __restrict__ A, const float* __restrict__ W,
    const float* __restrict__ bias, float* __restrict__ out,
    int N, int K)
{
    __shared__ __align__(16) float At[16][68];
    __shared__ __align__(16) float Bt[16][68];
    int tid = threadIdx.x;
    int ty = tid >> 4, tx = tid & 15;
    int rowbase = blockIdx.x * 64;
    int colbase = blockIdx.y * 64;
    int ar = tid >> 2, akq = tid & 3;
    int bk = tid >> 4, bnq = tid & 15;
    const float* Arow = A + (size_t)(rowbase + ar) * K + akq * 4;
    const float* Wp = W + (size_t)bk * N + colbase + bnq * 4;

    float acc[4][4] = {};
    for (int k0 = 0; k0 < K; k0 += 16) {
        float4 av = *(const float4*)(Arow + k0);
        float4 bv = *(const float4*)(Wp + (size_t)k0 * N);
        __syncthreads();
        At[akq*4+0][ar] = av.x; At[akq*4+1][ar] = av.y;
        At[akq*4+2][ar] = av.z; At[akq*4+3][ar] = av.w;
        *(float4*)&Bt[bk][bnq*4] = bv;
        __syncthreads();
        #pragma unroll
        for (int k = 0; k < 16; ++k) {
            float4 a4 = *(const float4*)&At[k][ty*4];
            float4 b4 = *(const float4*)&Bt[k][tx*4];
            float a[4] = {a4.x, a4.y, a4.z, a4.w};
            float b[4] = {b4.x, b4.y, b4.z, b4.w};
            #pragma unroll
            for (int i = 0; i < 4; ++i)
                #pragma unroll
                for (int j = 0; j < 4; ++j)
                    acc[i][j] = fmaf(a[i], b[j], acc[i][j]);
        }
    }
    #pragma unroll
    for (int i = 0; i < 4; ++i) {
        int rr = rowbase + ty*4 + i;
        int cc = colbase + tx*4;
        float4 o;
        o.x = fmaxf(acc[i][0] + bias[cc+0], 0.f);
        o.y = fmaxf(acc[i][1] + bias[cc+1], 0.f);
        o.z = fmaxf(acc[i][2] + bias[cc+2], 0.f);
        o.w = fmaxf(acc[i][3] + bias[cc+3], 0.f);
        *(float4*)&out[(size_t)rr * N + cc] = o;
    }
}

// ---------------- MFMA bf16 Gram GEMM, symmetric (lower-triangle blocks) ----------------
// 2080 blocks; block (bi,bj), bi>=bj. Off-diagonal blocks write both the (bi,bj)
// tile and its transpose. dh[i][j] = fp16(sq[j] - 2*dot(x_i,x_j)).
__global__ void __launch_bounds__(256) dist_gemm_kernel(
    const unsigned short* __restrict__ xb, const float* __restrict__ sq,
    __half* __restrict__ dh)
{
    __shared__ unsigned short Abuf[128 * 32];       // 8 KB
    __shared__ unsigned short Bbuf[128 * 32];       // 8 KB
    __shared__ __align__(16) __half Dt[128 * 132];  // 33 KB

    // triangular decode: bi >= bj
    int t = blockIdx.x;
    int bi = (int)((sqrtf(8.f * (float)t + 1.f) - 1.f) * 0.5f);
    while ((bi + 1) * (bi + 2) / 2 <= t) ++bi;
    while (bi * (bi + 1) / 2 > t) --bi;
    int bj = t - bi * (bi + 1) / 2;

    const int tid = threadIdx.x;
    const int wave = tid >> 6;
    const int lane = tid & 63;
    const int rowbase = bi * 128;
    const int colbase = bj * 128;
    const int wr = (wave >> 1) * 64;
    const int wc = (wave & 1) * 64;
    const int m16 = lane & 15;
    const int kq = lane >> 4;

    const int er0 = tid >> 2;
    const int er1 = 64 + (tid >> 2);
    const int eko = tid & 3;

    f32x4 acc[4][4];
    #pragma unroll
    for (int a = 0; a < 4; ++a)
        #pragma unroll
        for (int b = 0; b < 4; ++b)
            acc[a][b] = (f32x4){0.f, 0.f, 0.f, 0.f};

    for (int kb = 0; kb < DDIM / 32; ++kb) {
        const int k0 = kb * 32;
        __syncthreads();
        __builtin_amdgcn_global_load_lds(
            (const __attribute__((address_space(1))) void*)(xb + (size_t)(rowbase + er0) * DDIM + k0 + eko * 8),
            (__attribute__((address_space(3))) void*)((char*)Abuf + (wave * 64) * 16),
            16, 0, 0);
        __builtin_amdgcn_global_load_lds(
            (const __attribute__((address_space(1))) void*)(xb + (size_t)(rowbase + er1) * DDIM + k0 + eko * 8),
            (__attribute__((address_space(3))) void*)((char*)Abuf + (256 + wave * 64) * 16),
            16, 0, 0);
        __builtin_amdgcn_global_load_lds(
            (const __attribute__((address_space(1))) void*)(xb + (size_t)(colbase + er0) * DDIM + k0 + eko * 8),
            (__attribute__((address_space(3))) void*)((char*)Bbuf + (wave * 64) * 16),
            16, 0, 0);
        __builtin_amdgcn_global_load_lds(
            (const __attribute__((address_space(1))) void*)(xb + (size_t)(colbase + er1) * DDIM + k0 + eko * 8),
            (__attribute__((address_space(3))) void*)((char*)Bbuf + (256 + wave * 64) * 16),
            16, 0, 0);
        __syncthreads();

        bf16x8 af[4], bfr[4];
        #pragma unroll
        for (int s = 0; s < 4; ++s) {
            af[s]  = *(const bf16x8*)&Abuf[(wr + s * 16 + m16) * 32 + kq * 8];
            bfr[s] = *(const bf16x8*)&Bbuf[(wc + s * 16 + m16) * 32 + kq * 8];
        }
        #pragma unroll
        for (int si = 0; si < 4; ++si)
            #pragma unroll
            for (int sj = 0; sj < 4; ++sj)
                acc[si][sj] = __builtin_amdgcn_mfma_f32_16x16x32_bf16(
                    af[si], bfr[sj], acc[si][sj], 0, 0, 0);
    }

    // ---- pass 1: normal tile ----
    float sqc[4];
    #pragma unroll
    for (int sj = 0; sj < 4; ++sj) sqc[sj] = sq[colbase + wc + sj * 16 + m16];

    #pragma unroll
    for (int si = 0; si < 4; ++si)
        #pragma unroll
        for (int sj = 0; sj < 4; ++sj) {
            int r = wr + si * 16 + kq * 4;
            int c = wc + sj * 16 + m16;
            #pragma unroll
            for (int v = 0; v < 4; ++v)
                Dt[(r + v) * 132 + c] = __float2half(sqc[sj] - 2.0f * acc[si][sj][v]);
        }
    __syncthreads();

    #pragma unroll
    for (int it = 0; it < 8; ++it) {
        int r = it * 16 + (tid >> 4);
        int ch = tid & 15;
        const __half* p = &Dt[r * 132 + ch * 8];
        union { uint2 q[2]; float4 f; } u;
        u.q[0] = *(const uint2*)p;
        u.q[1] = *(const uint2*)(p + 4);
        *(float4*)&dh[(size_t)(rowbase + r) * NROWS + colbase + ch * 8] = u.f;
    }

    // ---- pass 2: transposed tile (off-diagonal blocks only) ----
    if (bi != bj) {
        __syncthreads();   // pass-1 LDS reads done before overwrite
        #pragma unroll
        for (int si = 0; si < 4; ++si) {
            float4 sqr4 = *(const float4*)&sq[rowbase + wr + si * 16 + kq * 4];
            float sr[4] = {sqr4.x, sqr4.y, sqr4.z, sqr4.w};
            #pragma unroll
            for (int sj = 0; sj < 4; ++sj) {
                int r = wr + si * 16 + kq * 4;
                int c = wc + sj * 16 + m16;
                __half h4[4];
                #pragma unroll
                for (int v = 0; v < 4; ++v)
                    h4[v] = __float2half(sr[v] - 2.0f * acc[si][sj][v]);
                *(double*)&Dt[c * 132 + r] = *(double*)h4;   // 8B packed write
            }
        }
        __syncthreads();
        #pragma unroll
        for (int it = 0; it < 8; ++it) {
            int r = it * 16 + (tid >> 4);       // row of transposed tile = original col
            int ch = tid & 15;
            const __half* p = &Dt[r * 132 + ch * 8];
            union { uint2 q[2]; float4 f; } u;
            u.q[0] = *(const uint2*)p;
            u.q[1] = *(const uint2*)(p + 4);
            *(float4*)&dh[(size_t)(colbase + r) * NROWS + rowbase + ch * 8] = u.f;
        }
    }
}

// ---------------- streaming per-row top-32 screen (1 wave / row) ----------------
__global__ void __launch_bounds__(256) select_kernel(
    const __half* __restrict__ dh, int* __restrict__ cand)
{
    int row = blockIdx.x * 4 + (threadIdx.x >> 6);
    int lane = threadIdx.x & 63;
    const __half* rp = dh + (size_t)row * NROWS;

    float dv[8]; int jv[8];
    #pragma unroll
    for (int t = 0; t < 8; ++t) { dv[t] = INFINITY; jv[t] = 0x7fffffff; }

    // 4-deep software pipeline of 16B loads
    float4 buf[4];
    #pragma unroll
    for (int p = 0; p < 4; ++p)
        buf[p] = *(const float4*)(rp + p * 512 + lane * 8);

    for (int step = 0; step < NROWS / 512; ++step) {
        union { float4 f; f16x8 h; } u;
        u.f = buf[step & 3];
        if (step + 4 < NROWS / 512)
            buf[step & 3] = *(const float4*)(rp + (step + 4) * 512 + lane * 8);
        // packed fp16 min tree (v_pk_min_f16 via elementwise builtin)
        f16x4 lo = __builtin_shufflevector(u.h, u.h, 0, 1, 2, 3);
        f16x4 hi = __builtin_shufflevector(u.h, u.h, 4, 5, 6, 7);
        f16x4 m4 = __builtin_elementwise_min(lo, hi);
        f16x2 m2 = __builtin_elementwise_min(
            __builtin_shufflevector(m4, m4, 0, 1),
            __builtin_shufflevector(m4, m4, 2, 3));
        float m = fminf((float)m2[0], (float)m2[1]);
        if (m < dv[7]) {
            int col0 = step * 512 + lane * 8;
            #pragma unroll
            for (int t = 0; t < 8; ++t) {
                float d = (float)u.h[t];
                if (d < dv[7]) {
                    dv[7] = d; jv[7] = col0 + t;
                    #pragma unroll
                    for (int q = 7; q > 0; --q) {
                        if (dv[q] < dv[q-1]) {
                            float td = dv[q]; dv[q] = dv[q-1]; dv[q-1] = td;
                            int tj = jv[q]; jv[q] = jv[q-1]; jv[q-1] = tj;
                        }
                    }
                }
            }
        }
    }

    // wave-wide extraction of top-32 (approx; exact rescore follows)
    float cur = dv[0];
    for (int t = 0; t < 32; ++t) {
        float m = cur;
        #pragma unroll
        for (int off = 32; off > 0; off >>= 1) m = fminf(m, __shfl_xor(m, off));
        unsigned long long b = __ballot(cur == m);
        int first = (int)(__ffsll((unsigned long long)b) - 1);
        if (lane == first) {
            cand[(size_t)row * 32 + t] = jv[0];
            #pragma unroll
            for (int q = 0; q < 7; ++q) { dv[q] = dv[q+1]; jv[q] = jv[q+1]; }
            dv[7] = INFINITY;
            cur = dv[0];
        }
    }
}

// ---------------- exact fp32 rescore of 32 candidates -> final sorted top-16 ----------------
__global__ void __launch_bounds__(256) rescore_kernel(
    const float* __restrict__ x, const float* __restrict__ sq,
    const int* __restrict__ cand, int* __restrict__ idxOut)
{
    int row = blockIdx.x * 4 + (threadIdx.x >> 6);
    int lane = threadIdx.x & 63;
    float xr[6];
    #pragma unroll
    for (int q = 0; q < 6; ++q) xr[q] = x[(size_t)row * DDIM + lane + 64 * q];
    int myj = cand[(size_t)row * 32 + (lane & 31)];
    float sqrow = sq[row];
    float myd = 0.f;
    for (int c = 0; c < 32; ++c) {
        int j = __shfl(myj, c);
        const float* xc = x + (size_t)j * DDIM;
        float p = 0.f;
        #pragma unroll
        for (int q = 0; q < 6; ++q) p = fmaf(xr[q], xc[lane + 64 * q], p);
        #pragma unroll
        for (int off = 32; off > 0; off >>= 1) p += __shfl_xor(p, off);
        float d = sqrow + sq[j] - 2.f * p;
        if (lane == c) myd = d;
    }
    int rank = 0;
    for (int t = 0; t < 32; ++t) {
        float dt = __shfl(myd, t); int jt = __shfl(myj, t);
        if (dj_better(dt, jt, myd, myj)) ++rank;
    }
    if (lane < 32 && rank < 16) idxOut[(size_t)row * 16 + rank] = myj;
}

// ---------------- gather-mean: agg[row] = mean of first k neighbors' h ----------------
__global__ void __launch_bounds__(256) aggregate_kernel(
    const float* __restrict__ h, const int* __restrict__ idx, const int* __restrict__ kk,
    float* __restrict__ agg)
{
    int row = blockIdx.x, tid = threadIdx.x;
    __shared__ int sidx[16];
    __shared__ int sk;
    if (tid < 16) sidx[tid] = idx[(size_t)row * 16 + tid];
    if (tid == 0) sk = kk[row];
    __syncthreads();
    int k = sk;
    float acc = 0.f;
    for (int t = 0; t < k; ++t) acc += h[(size_t)sidx[t] * HDIM + tid];
    agg[(size_t)row * HDIM + tid] = acc / (float)k;
}

// ---------------- LayerNorm(h + r) * g + b, then @ W_fc + b_fc ----------------
__global__ void __launch_bounds__(256) ln_fc_kernel(
    const float* __restrict__ h, const float* __restrict__ r,
    const float* __restrict__ g, const float* __restrict__ bb,
    const float* __restrict__ W_fc, const float* __restrict__ b_fc,
    float* __restrict__ out)
{
    int row = blockIdx.x, tid = threadIdx.x;
    int wave = tid >> 6, lane = tid & 63;
    float z = h[(size_t)row * HDIM + tid] + r[(size_t)row * HDIM + tid];
    float s = z, s2 = z * z;
    #pragma unroll
    for (int off = 32; off > 0; off >>= 1) { s += __shfl_xor(s, off); s2 += __shfl_xor(s2, off); }
    __shared__ float red[8];
    __shared__ float smv[2];
    if (lane == 0) { red[wave] = s; red[4 + wave] = s2; }
    __syncthreads();
    if (tid == 0) {
        float ts = red[0] + red[1] + red[2] + red[3];
        float t2 = red[4] + red[5] + red[6] + red[7];
        float mu = ts / 256.f;
        float var = t2 / 256.f - mu * mu;
        smv[0] = mu; smv[1] = rsqrtf(var + LN_EPS);
    }
    __syncthreads();
    float zn = (z - smv[0]) * smv[1];
    float val = zn * g[tid] + bb[tid];
    float p[6];
    #pragma unroll
    for (int c = 0; c < 6; ++c) p[c] = val * W_fc[tid * 6 + c];
    #pragma unroll
    for (int c = 0; c < 6; ++c)
        #pragma unroll
        for (int off = 32; off > 0; off >>= 1) p[c] += __shfl_xor(p[c], off);
    __shared__ float pr[4][6];
    if (lane == 0) {
        #pragma unroll
        for (int c = 0; c < 6; ++c) pr[wave][c] = p[c];
    }
    __syncthreads();
    if (tid < 6)
        out[(size_t)row * CDIM + tid] = pr[0][tid] + pr[1][tid] + pr[2][tid] + pr[3][tid] + b_fc[tid];
}

extern "C" void kernel_launch(void* const* d_in, const int* in_sizes, int n_in,
                              void* d_out, int out_size, void* d_ws, size_t ws_size,
                              hipStream_t stream) {
    const float* x      = (const float*)d_in[0];
    const float* W_proj = (const float*)d_in[1];
    const float* b_proj = (const float*)d_in[2];
    const float* W_tau  = (const float*)d_in[3];
    const float* b_tau  = (const float*)d_in[4];
    const float* W_res  = (const float*)d_in[5];
    const float* b_res  = (const float*)d_in[6];
    const float* ln_g   = (const float*)d_in[7];
    const float* ln_b   = (const float*)d_in[8];
    const float* W_fc   = (const float*)d_in[9];
    const float* b_fc   = (const float*)d_in[10];
    float* out = (float*)d_out;

    char* ws = (char*)d_ws;
    float* sq   = (float*)ws;                        ws += (size_t)NROWS * 4;
    int*   kk   = (int*)ws;                          ws += (size_t)NROWS * 4;
    float* h    = (float*)ws;                        ws += (size_t)NROWS * HDIM * 4;
    float* agg  = (float*)ws;                        ws += (size_t)NROWS * HDIM * 4;
    float* r    = (float*)ws;                        ws += (size_t)NROWS * HDIM * 4;
    int*   idx  = (int*)ws;                          ws += (size_t)NROWS * 16 * 4;
    int*   cand = (int*)ws;                          ws += (size_t)NROWS * 32 * 4;
    unsigned short* xb = (unsigned short*)ws;        ws += (size_t)NROWS * DDIM * 2;
    ws = (char*)(((size_t)ws + 255) & ~(size_t)255);
    __half* dh  = (__half*)ws;                       ws += (size_t)NROWS * NROWS * 2;

    tobf16_kernel<<<NROWS * DDIM / 256, 256, 0, stream>>>(x, xb);
    precompute_kernel<<<NROWS / 4, 256, 0, stream>>>(x, W_tau, b_tau, sq, kk);
    gemm_bias_relu_kernel<<<dim3(NROWS / 64, HDIM / 64), 256, 0, stream>>>(
        x, W_proj, b_proj, h, HDIM, DDIM);
    dist_gemm_kernel<<<(NROWS/128) * (NROWS/128 + 1) / 2, 256, 0, stream>>>(xb, sq, dh);
    select_kernel<<<NROWS / 4, 256, 0, stream>>>(dh, cand);
    rescore_kernel<<<NROWS / 4, 256, 0, stream>>>(x, sq, cand, idx);
    aggregate_kernel<<<NROWS, 256, 0, stream>>>(h, idx, kk, agg);
    gemm_bias_relu_kernel<<<dim3(NROWS / 64, HDIM / 64), 256, 0, stream>>>(
        agg, W_res, b_res, r, HDIM, HDIM);
    ln_fc_kernel<<<NROWS, 256, 0, stream>>>(h, r, ln_g, ln_b, W_fc, b_fc, out);
}

// Round 6
// 371.297 us; speedup vs baseline: 1.0834x; 1.0834x over previous
//
#include <hip/hip_runtime.h>
#include <hip/hip_fp16.h>
#include <math.h>

#define NROWS 8192
#define DDIM 384
#define HDIM 256
#define CDIM 6
#define LN_EPS 1e-5f

typedef short bf16x8 __attribute__((ext_vector_type(8)));
typedef float f32x4 __attribute__((ext_vector_type(4)));
typedef _Float16 f16x8 __attribute__((ext_vector_type(8)));
typedef _Float16 f16x4 __attribute__((ext_vector_type(4)));
typedef _Float16 f16x2 __attribute__((ext_vector_type(2)));

__device__ __forceinline__ bool dj_better(float d1, int j1, float d2, int j2) {
    return (d1 < d2) || (d1 == d2 && j1 < j2);
}

// ---------------- x (fp32) -> bf16 bits, round-to-nearest-even ----------------
__global__ void __launch_bounds__(256) tobf16_kernel(
    const float* __restrict__ x, unsigned short* __restrict__ xb)
{
    int i = blockIdx.x * 256 + threadIdx.x;
    unsigned int u = __float_as_uint(x[i]);
    u += 0x7fffu + ((u >> 16) & 1u);
    xb[i] = (unsigned short)(u >> 16);
}

// ---------------- sq[i] = ||x_i||^2, k[i] from tau ----------------
__global__ void __launch_bounds__(256) precompute_kernel(
    const float* __restrict__ x, const float* __restrict__ W_tau,
    const float* __restrict__ b_tau, float* __restrict__ sq, int* __restrict__ kk)
{
    int tid = threadIdx.x;
    int wave = tid >> 6, lane = tid & 63;
    int row = blockIdx.x * 4 + wave;
    const float* xr = x + (size_t)row * DDIM;
    float s = 0.f, tp = 0.f;
    #pragma unroll
    for (int q = 0; q < 6; ++q) {
        float v = xr[lane + 64 * q];
        s = fmaf(v, v, s);
        tp = fmaf(v, W_tau[lane + 64 * q], tp);
    }
    #pragma unroll
    for (int off = 32; off > 0; off >>= 1) {
        s += __shfl_xor(s, off);
        tp += __shfl_xor(tp, off);
    }
    if (lane == 0) {
        sq[row] = s;
        float u = tp + b_tau[0];
        float tau = 1.f / (1.f + expf(-u));
        float kf = rintf(16.f - 12.f * tau);
        int k = (int)kf;
        k = min(16, max(1, k));
        kk[row] = k;
    }
}

// ---------------- fp32 tiled GEMM: out = relu(A[M,K] @ W[K,N] + bias) ----------------
__global__ void __launch_bounds__(256) gemm_bias_relu_kernel(
    const float* __restrict__ A, const float* __restrict__ W,
    const float* __restrict__ bias, float* __restrict__ out,
    int N, int K)
{
    __shared__ __align__(16) float At[16][68];
    __shared__ __align__(16) float Bt[16][68];
    int tid = threadIdx.x;
    int ty = tid >> 4, tx = tid & 15;
    int rowbase = blockIdx.x * 64;
    int colbase = blockIdx.y * 64;
    int ar = tid >> 2, akq = tid & 3;
    int bk = tid >> 4, bnq = tid & 15;
    const float* Arow = A + (size_t)(rowbase + ar) * K + akq * 4;
    const float* Wp = W + (size_t)bk * N + colbase + bnq * 4;

    float acc[4][4] = {};
    for (int k0 = 0; k0 < K; k0 += 16) {
        float4 av = *(const float4*)(Arow + k0);
        float4 bv = *(const float4*)(Wp + (size_t)k0 * N);
        __syncthreads();
        At[akq*4+0][ar] = av.x; At[akq*4+1][ar] = av.y;
        At[akq*4+2][ar] = av.z; At[akq*4+3][ar] = av.w;
        *(float4*)&Bt[bk][bnq*4] = bv;
        __syncthreads();
        #pragma unroll
        for (int k = 0; k < 16; ++k) {
            float4 a4 = *(const float4*)&At[k][ty*4];
            float4 b4 = *(const float4*)&Bt[k][tx*4];
            float a[4] = {a4.x, a4.y, a4.z, a4.w};
            float b[4] = {b4.x, b4.y, b4.z, b4.w};
            #pragma unroll
            for (int i = 0; i < 4; ++i)
                #pragma unroll
                for (int j = 0; j < 4; ++j)
                    acc[i][j] = fmaf(a[i], b[j], acc[i][j]);
        }
    }
    #pragma unroll
    for (int i = 0; i < 4; ++i) {
        int rr = rowbase + ty*4 + i;
        int cc = colbase + tx*4;
        float4 o;
        o.x = fmaxf(acc[i][0] + bias[cc+0], 0.f);
        o.y = fmaxf(acc[i][1] + bias[cc+1], 0.f);
        o.z = fmaxf(acc[i][2] + bias[cc+2], 0.f);
        o.w = fmaxf(acc[i][3] + bias[cc+3], 0.f);
        *(float4*)&out[(size_t)rr * N + cc] = o;
    }
}

// ---------------- MFMA bf16 Gram GEMM, symmetric (lower-triangle blocks) ----------------
__global__ void __launch_bounds__(256) dist_gemm_kernel(
    const unsigned short* __restrict__ xb, const float* __restrict__ sq,
    __half* __restrict__ dh)
{
    __shared__ unsigned short Abuf[128 * 32];       // 8 KB
    __shared__ unsigned short Bbuf[128 * 32];       // 8 KB
    __shared__ __align__(16) __half Dt[128 * 132];  // 33 KB

    // triangular decode: bi >= bj
    int t = blockIdx.x;
    int bi = (int)((sqrtf(8.f * (float)t + 1.f) - 1.f) * 0.5f);
    while ((bi + 1) * (bi + 2) / 2 <= t) ++bi;
    while (bi * (bi + 1) / 2 > t) --bi;
    int bj = t - bi * (bi + 1) / 2;

    const int tid = threadIdx.x;
    const int wave = tid >> 6;
    const int lane = tid & 63;
    const int rowbase = bi * 128;
    const int colbase = bj * 128;
    const int wr = (wave >> 1) * 64;
    const int wc = (wave & 1) * 64;
    const int m16 = lane & 15;
    const int kq = lane >> 4;

    const int er0 = tid >> 2;
    const int er1 = 64 + (tid >> 2);
    const int eko = tid & 3;

    f32x4 acc[4][4];
    #pragma unroll
    for (int a = 0; a < 4; ++a)
        #pragma unroll
        for (int b = 0; b < 4; ++b)
            acc[a][b] = (f32x4){0.f, 0.f, 0.f, 0.f};

    for (int kb = 0; kb < DDIM / 32; ++kb) {
        const int k0 = kb * 32;
        __syncthreads();
        __builtin_amdgcn_global_load_lds(
            (const __attribute__((address_space(1))) void*)(xb + (size_t)(rowbase + er0) * DDIM + k0 + eko * 8),
            (__attribute__((address_space(3))) void*)((char*)Abuf + (wave * 64) * 16),
            16, 0, 0);
        __builtin_amdgcn_global_load_lds(
            (const __attribute__((address_space(1))) void*)(xb + (size_t)(rowbase + er1) * DDIM + k0 + eko * 8),
            (__attribute__((address_space(3))) void*)((char*)Abuf + (256 + wave * 64) * 16),
            16, 0, 0);
        __builtin_amdgcn_global_load_lds(
            (const __attribute__((address_space(1))) void*)(xb + (size_t)(colbase + er0) * DDIM + k0 + eko * 8),
            (__attribute__((address_space(3))) void*)((char*)Bbuf + (wave * 64) * 16),
            16, 0, 0);
        __builtin_amdgcn_global_load_lds(
            (const __attribute__((address_space(1))) void*)(xb + (size_t)(colbase + er1) * DDIM + k0 + eko * 8),
            (__attribute__((address_space(3))) void*)((char*)Bbuf + (256 + wave * 64) * 16),
            16, 0, 0);
        __syncthreads();

        bf16x8 af[4], bfr[4];
        #pragma unroll
        for (int s = 0; s < 4; ++s) {
            af[s]  = *(const bf16x8*)&Abuf[(wr + s * 16 + m16) * 32 + kq * 8];
            bfr[s] = *(const bf16x8*)&Bbuf[(wc + s * 16 + m16) * 32 + kq * 8];
        }
        #pragma unroll
        for (int si = 0; si < 4; ++si)
            #pragma unroll
            for (int sj = 0; sj < 4; ++sj)
                acc[si][sj] = __builtin_amdgcn_mfma_f32_16x16x32_bf16(
                    af[si], bfr[sj], acc[si][sj], 0, 0, 0);
    }

    // ---- pass 1: normal tile ----
    float sqc[4];
    #pragma unroll
    for (int sj = 0; sj < 4; ++sj) sqc[sj] = sq[colbase + wc + sj * 16 + m16];

    #pragma unroll
    for (int si = 0; si < 4; ++si)
        #pragma unroll
        for (int sj = 0; sj < 4; ++sj) {
            int r = wr + si * 16 + kq * 4;
            int c = wc + sj * 16 + m16;
            #pragma unroll
            for (int v = 0; v < 4; ++v)
                Dt[(r + v) * 132 + c] = __float2half(sqc[sj] - 2.0f * acc[si][sj][v]);
        }
    __syncthreads();

    #pragma unroll
    for (int it = 0; it < 8; ++it) {
        int r = it * 16 + (tid >> 4);
        int ch = tid & 15;
        const __half* p = &Dt[r * 132 + ch * 8];
        union { uint2 q[2]; float4 f; } u;
        u.q[0] = *(const uint2*)p;
        u.q[1] = *(const uint2*)(p + 4);
        *(float4*)&dh[(size_t)(rowbase + r) * NROWS + colbase + ch * 8] = u.f;
    }

    // ---- pass 2: transposed tile (off-diagonal blocks only) ----
    if (bi != bj) {
        __syncthreads();
        #pragma unroll
        for (int si = 0; si < 4; ++si) {
            float4 sqr4 = *(const float4*)&sq[rowbase + wr + si * 16 + kq * 4];
            float sr[4] = {sqr4.x, sqr4.y, sqr4.z, sqr4.w};
            #pragma unroll
            for (int sj = 0; sj < 4; ++sj) {
                int r = wr + si * 16 + kq * 4;
                int c = wc + sj * 16 + m16;
                __half h4[4];
                #pragma unroll
                for (int v = 0; v < 4; ++v)
                    h4[v] = __float2half(sr[v] - 2.0f * acc[si][sj][v]);
                *(double*)&Dt[c * 132 + r] = *(double*)h4;
            }
        }
        __syncthreads();
        #pragma unroll
        for (int it = 0; it < 8; ++it) {
            int r = it * 16 + (tid >> 4);
            int ch = tid & 15;
            const __half* p = &Dt[r * 132 + ch * 8];
            union { uint2 q[2]; float4 f; } u;
            u.q[0] = *(const uint2*)p;
            u.q[1] = *(const uint2*)(p + 4);
            *(float4*)&dh[(size_t)(colbase + r) * NROWS + rowbase + ch * 8] = u.f;
        }
    }
}

// ---------------- streaming per-row top-32 screen (1 wave / row) ----------------
// Fully-unrolled 16-step stream with a 4-deep register pipeline (all array
// indices compile-time constant -> everything stays in VGPRs).
__global__ void __launch_bounds__(256) select_kernel(
    const __half* __restrict__ dh, int* __restrict__ cand)
{
    const int row = blockIdx.x * 4 + (threadIdx.x >> 6);
    const int lane = threadIdx.x & 63;
    const __half* rp = dh + (size_t)row * NROWS + lane * 8;

    float dv[8]; int jv[8];
    #pragma unroll
    for (int t = 0; t < 8; ++t) { dv[t] = INFINITY; jv[t] = 0x7fffffff; }

    float4 buf[4];
    #pragma unroll
    for (int p = 0; p < 4; ++p)
        buf[p] = *(const float4*)(rp + p * 512);

    #pragma unroll
    for (int step = 0; step < 16; ++step) {
        union { float4 f; f16x8 h; } u;
        u.f = buf[step & 3];                               // constant after unroll
        if (step + 4 < 16)
            buf[step & 3] = *(const float4*)(rp + (step + 4) * 512);

        f16x4 lo = __builtin_shufflevector(u.h, u.h, 0, 1, 2, 3);
        f16x4 hi = __builtin_shufflevector(u.h, u.h, 4, 5, 6, 7);
        f16x4 m4 = __builtin_elementwise_min(lo, hi);
        f16x2 m2 = __builtin_elementwise_min(
            __builtin_shufflevector(m4, m4, 0, 1),
            __builtin_shufflevector(m4, m4, 2, 3));
        float m = fminf((float)m2[0], (float)m2[1]);
        if (m < dv[7]) {
            int col0 = step * 512 + lane * 8;
            #pragma unroll
            for (int t = 0; t < 8; ++t) {
                float d = (float)u.h[t];
                if (d < dv[7]) {
                    dv[7] = d; jv[7] = col0 + t;
                    #pragma unroll
                    for (int q = 7; q > 0; --q) {
                        if (dv[q] < dv[q-1]) {
                            float td = dv[q]; dv[q] = dv[q-1]; dv[q-1] = td;
                            int tj = jv[q]; jv[q] = jv[q-1]; jv[q-1] = tj;
                        }
                    }
                }
            }
        }
    }

    // wave-wide extraction of top-32 (approx; exact rescore follows)
    float cur = dv[0];
    for (int t = 0; t < 32; ++t) {
        float m = cur;
        #pragma unroll
        for (int off = 32; off > 0; off >>= 1) m = fminf(m, __shfl_xor(m, off));
        unsigned long long b = __ballot(cur == m);
        int first = (int)(__ffsll((unsigned long long)b) - 1);
        if (lane == first) {
            cand[(size_t)row * 32 + t] = jv[0];
            #pragma unroll
            for (int q = 0; q < 7; ++q) { dv[q] = dv[q+1]; jv[q] = jv[q+1]; }
            dv[7] = INFINITY;
            cur = dv[0];
        }
    }
}

// ---------------- exact fp32 rescore of 32 candidates -> final sorted top-16 ----------------
__global__ void __launch_bounds__(256) rescore_kernel(
    const float* __restrict__ x, const float* __restrict__ sq,
    const int* __restrict__ cand, int* __restrict__ idxOut)
{
    int row = blockIdx.x * 4 + (threadIdx.x >> 6);
    int lane = threadIdx.x & 63;
    float xr[6];
    #pragma unroll
    for (int q = 0; q < 6; ++q) xr[q] = x[(size_t)row * DDIM + lane + 64 * q];
    int myj = cand[(size_t)row * 32 + (lane & 31)];
    float sqrow = sq[row];
    float myd = 0.f;
    for (int c = 0; c < 32; ++c) {
        int j = __shfl(myj, c);
        const float* xc = x + (size_t)j * DDIM;
        float p = 0.f;
        #pragma unroll
        for (int q = 0; q < 6; ++q) p = fmaf(xr[q], xc[lane + 64 * q], p);
        #pragma unroll
        for (int off = 32; off > 0; off >>= 1) p += __shfl_xor(p, off);
        float d = sqrow + sq[j] - 2.f * p;
        if (lane == c) myd = d;
    }
    int rank = 0;
    for (int t = 0; t < 32; ++t) {
        float dt = __shfl(myd, t); int jt = __shfl(myj, t);
        if (dj_better(dt, jt, myd, myj)) ++rank;
    }
    if (lane < 32 && rank < 16) idxOut[(size_t)row * 16 + rank] = myj;
}

// ---------------- gather-mean: agg[row] = mean of first k neighbors' h ----------------
__global__ void __launch_bounds__(256) aggregate_kernel(
    const float* __restrict__ h, const int* __restrict__ idx, const int* __restrict__ kk,
    float* __restrict__ agg)
{
    int row = blockIdx.x, tid = threadIdx.x;
    __shared__ int sidx[16];
    __shared__ int sk;
    if (tid < 16) sidx[tid] = idx[(size_t)row * 16 + tid];
    if (tid == 0) sk = kk[row];
    __syncthreads();
    int k = sk;
    float acc = 0.f;
    for (int t = 0; t < k; ++t) acc += h[(size_t)sidx[t] * HDIM + tid];
    agg[(size_t)row * HDIM + tid] = acc / (float)k;
}

// ---------------- LayerNorm(h + r) * g + b, then @ W_fc + b_fc ----------------
__global__ void __launch_bounds__(256) ln_fc_kernel(
    const float* __restrict__ h, const float* __restrict__ r,
    const float* __restrict__ g, const float* __restrict__ bb,
    const float* __restrict__ W_fc, const float* __restrict__ b_fc,
    float* __restrict__ out)
{
    int row = blockIdx.x, tid = threadIdx.x;
    int wave = tid >> 6, lane = tid & 63;
    float z = h[(size_t)row * HDIM + tid] + r[(size_t)row * HDIM + tid];
    float s = z, s2 = z * z;
    #pragma unroll
    for (int off = 32; off > 0; off >>= 1) { s += __shfl_xor(s, off); s2 += __shfl_xor(s2, off); }
    __shared__ float red[8];
    __shared__ float smv[2];
    if (lane == 0) { red[wave] = s; red[4 + wave] = s2; }
    __syncthreads();
    if (tid == 0) {
        float ts = red[0] + red[1] + red[2] + red[3];
        float t2 = red[4] + red[5] + red[6] + red[7];
        float mu = ts / 256.f;
        float var = t2 / 256.f - mu * mu;
        smv[0] = mu; smv[1] = rsqrtf(var + LN_EPS);
    }
    __syncthreads();
    float zn = (z - smv[0]) * smv[1];
    float val = zn * g[tid] + bb[tid];
    float p[6];
    #pragma unroll
    for (int c = 0; c < 6; ++c) p[c] = val * W_fc[tid * 6 + c];
    #pragma unroll
    for (int c = 0; c < 6; ++c)
        #pragma unroll
        for (int off = 32; off > 0; off >>= 1) p[c] += __shfl_xor(p[c], off);
    __shared__ float pr[4][6];
    if (lane == 0) {
        #pragma unroll
        for (int c = 0; c < 6; ++c) pr[wave][c] = p[c];
    }
    __syncthreads();
    if (tid < 6)
        out[(size_t)row * CDIM + tid] = pr[0][tid] + pr[1][tid] + pr[2][tid] + pr[3][tid] + b_fc[tid];
}

extern "C" void kernel_launch(void* const* d_in, const int* in_sizes, int n_in,
                              void* d_out, int out_size, void* d_ws, size_t ws_size,
                              hipStream_t stream) {
    const float* x      = (const float*)d_in[0];
    const float* W_proj = (const float*)d_in[1];
    const float* b_proj = (const float*)d_in[2];
    const float* W_tau  = (const float*)d_in[3];
    const float* b_tau  = (const float*)d_in[4];
    const float* W_res  = (const float*)d_in[5];
    const float* b_res  = (const float*)d_in[6];
    const float* ln_g   = (const float*)d_in[7];
    const float* ln_b   = (const float*)d_in[8];
    const float* W_fc   = (const float*)d_in[9];
    const float* b_fc   = (const float*)d_in[10];
    float* out = (float*)d_out;

    char* ws = (char*)d_ws;
    float* sq   = (float*)ws;                        ws += (size_t)NROWS * 4;
    int*   kk   = (int*)ws;                          ws += (size_t)NROWS * 4;
    float* h    = (float*)ws;                        ws += (size_t)NROWS * HDIM * 4;
    float* agg  = (float*)ws;                        ws += (size_t)NROWS * HDIM * 4;
    float* r    = (float*)ws;                        ws += (size_t)NROWS * HDIM * 4;
    int*   idx  = (int*)ws;                          ws += (size_t)NROWS * 16 * 4;
    int*   cand = (int*)ws;                          ws += (size_t)NROWS * 32 * 4;
    unsigned short* xb = (unsigned short*)ws;        ws += (size_t)NROWS * DDIM * 2;
    ws = (char*)(((size_t)ws + 255) & ~(size_t)255);
    __half* dh  = (__half*)ws;                       ws += (size_t)NROWS * NROWS * 2;

    tobf16_kernel<<<NROWS * DDIM / 256, 256, 0, stream>>>(x, xb);
    precompute_kernel<<<NROWS / 4, 256, 0, stream>>>(x, W_tau, b_tau, sq, kk);
    gemm_bias_relu_kernel<<<dim3(NROWS / 64, HDIM / 64), 256, 0, stream>>>(
        x, W_proj, b_proj, h, HDIM, DDIM);
    dist_gemm_kernel<<<(NROWS/128) * (NROWS/128 + 1) / 2, 256, 0, stream>>>(xb, sq, dh);
    select_kernel<<<NROWS / 4, 256, 0, stream>>>(dh, cand);
    rescore_kernel<<<NROWS / 4, 256, 0, stream>>>(x, sq, cand, idx);
    aggregate_kernel<<<NROWS, 256, 0, stream>>>(h, idx, kk, agg);
    gemm_bias_relu_kernel<<<dim3(NROWS / 64, HDIM / 64), 256, 0, stream>>>(
        agg, W_res, b_res, r, HDIM, HDIM);
    ln_fc_kernel<<<NROWS, 256, 0, stream>>>(h, r, ln_g, ln_b, W_fc, b_fc, out);
}

// Round 7
// 319.733 us; speedup vs baseline: 1.2581x; 1.1613x over previous
//
#include <hip/hip_runtime.h>
#include <hip/hip_fp16.h>
#include <math.h>

#define NROWS 8192
#define DDIM 384
#define HDIM 256
#define CDIM 6
#define LN_EPS 1e-5f

typedef short bf16x8 __attribute__((ext_vector_type(8)));
typedef float f32x4 __attribute__((ext_vector_type(4)));
typedef unsigned short u16x8 __attribute__((ext_vector_type(8)));
typedef unsigned short u16x4 __attribute__((ext_vector_type(4)));
typedef unsigned short u16x2 __attribute__((ext_vector_type(2)));

__device__ __forceinline__ bool dj_better(float d1, int j1, float d2, int j2) {
    return (d1 < d2) || (d1 == d2 && j1 < j2);
}

__device__ __forceinline__ unsigned int umin_(unsigned int a, unsigned int b) { return a < b ? a : b; }
__device__ __forceinline__ unsigned int umax_(unsigned int a, unsigned int b) { return a > b ? a : b; }

// fp32 -> fp16 -> monotonic u16 (unsigned order == float order)
__device__ __forceinline__ unsigned short map16(float v) {
    unsigned short b = __half_as_ushort(__float2half(v));
    return (unsigned short)(b ^ (unsigned short)((((short)b) >> 15) | 0x8000));
}

// ---------------- x (fp32) -> bf16 bits, round-to-nearest-even ----------------
__global__ void __launch_bounds__(256) tobf16_kernel(
    const float* __restrict__ x, unsigned short* __restrict__ xb)
{
    int i = blockIdx.x * 256 + threadIdx.x;
    unsigned int u = __float_as_uint(x[i]);
    u += 0x7fffu + ((u >> 16) & 1u);
    xb[i] = (unsigned short)(u >> 16);
}

// ---------------- sq[i] = ||x_i||^2, k[i] from tau ----------------
__global__ void __launch_bounds__(256) precompute_kernel(
    const float* __restrict__ x, const float* __restrict__ W_tau,
    const float* __restrict__ b_tau, float* __restrict__ sq, int* __restrict__ kk)
{
    int tid = threadIdx.x;
    int wave = tid >> 6, lane = tid & 63;
    int row = blockIdx.x * 4 + wave;
    const float* xr = x + (size_t)row * DDIM;
    float s = 0.f, tp = 0.f;
    #pragma unroll
    for (int q = 0; q < 6; ++q) {
        float v = xr[lane + 64 * q];
        s = fmaf(v, v, s);
        tp = fmaf(v, W_tau[lane + 64 * q], tp);
    }
    #pragma unroll
    for (int off = 32; off > 0; off >>= 1) {
        s += __shfl_xor(s, off);
        tp += __shfl_xor(tp, off);
    }
    if (lane == 0) {
        sq[row] = s;
        float u = tp + b_tau[0];
        float tau = 1.f / (1.f + expf(-u));
        float kf = rintf(16.f - 12.f * tau);
        int k = (int)kf;
        k = min(16, max(1, k));
        kk[row] = k;
    }
}

// ---------------- fp32 tiled GEMM: out = relu(A[M,K] @ W[K,N] + bias) ----------------
__global__ void __launch_bounds__(256) gemm_bias_relu_kernel(
    const float* __restrict__ A, const float* __restrict__ W,
    const float* __restrict__ bias, float* __restrict__ out,
    int N, int K)
{
    __shared__ __align__(16) float At[16][68];
    __shared__ __align__(16) float Bt[16][68];
    int tid = threadIdx.x;
    int ty = tid >> 4, tx = tid & 15;
    int rowbase = blockIdx.x * 64;
    int colbase = blockIdx.y * 64;
    int ar = tid >> 2, akq = tid & 3;
    int bk = tid >> 4, bnq = tid & 15;
    const float* Arow = A + (size_t)(rowbase + ar) * K + akq * 4;
    const float* Wp = W + (size_t)bk * N + colbase + bnq * 4;

    float acc[4][4] = {};
    for (int k0 = 0; k0 < K; k0 += 16) {
        float4 av = *(const float4*)(Arow + k0);
        float4 bv = *(const float4*)(Wp + (size_t)k0 * N);
        __syncthreads();
        At[akq*4+0][ar] = av.x; At[akq*4+1][ar] = av.y;
        At[akq*4+2][ar] = av.z; At[akq*4+3][ar] = av.w;
        *(float4*)&Bt[bk][bnq*4] = bv;
        __syncthreads();
        #pragma unroll
        for (int k = 0; k < 16; ++k) {
            float4 a4 = *(const float4*)&At[k][ty*4];
            float4 b4 = *(const float4*)&Bt[k][tx*4];
            float a[4] = {a4.x, a4.y, a4.z, a4.w};
            float b[4] = {b4.x, b4.y, b4.z, b4.w};
            #pragma unroll
            for (int i = 0; i < 4; ++i)
                #pragma unroll
                for (int j = 0; j < 4; ++j)
                    acc[i][j] = fmaf(a[i], b[j], acc[i][j]);
        }
    }
    #pragma unroll
    for (int i = 0; i < 4; ++i) {
        int rr = rowbase + ty*4 + i;
        int cc = colbase + tx*4;
        float4 o;
        o.x = fmaxf(acc[i][0] + bias[cc+0], 0.f);
        o.y = fmaxf(acc[i][1] + bias[cc+1], 0.f);
        o.z = fmaxf(acc[i][2] + bias[cc+2], 0.f);
        o.w = fmaxf(acc[i][3] + bias[cc+3], 0.f);
        *(float4*)&out[(size_t)rr * N + cc] = o;
    }
}

// ---------------- MFMA bf16 Gram GEMM, symmetric (lower-triangle blocks) ----------------
// dz[i][j] = monotonic-u16( fp16( sq[j] - 2*dot(x_i,x_j) ) )
__global__ void __launch_bounds__(256) dist_gemm_kernel(
    const unsigned short* __restrict__ xb, const float* __restrict__ sq,
    unsigned short* __restrict__ dz)
{
    __shared__ unsigned short Abuf[128 * 32];       // 8 KB
    __shared__ unsigned short Bbuf[128 * 32];       // 8 KB
    __shared__ __align__(16) unsigned short Dt[128 * 132];  // 33 KB

    // triangular decode: bi >= bj
    int t = blockIdx.x;
    int bi = (int)((sqrtf(8.f * (float)t + 1.f) - 1.f) * 0.5f);
    while ((bi + 1) * (bi + 2) / 2 <= t) ++bi;
    while (bi * (bi + 1) / 2 > t) --bi;
    int bj = t - bi * (bi + 1) / 2;

    const int tid = threadIdx.x;
    const int wave = tid >> 6;
    const int lane = tid & 63;
    const int rowbase = bi * 128;
    const int colbase = bj * 128;
    const int wr = (wave >> 1) * 64;
    const int wc = (wave & 1) * 64;
    const int m16 = lane & 15;
    const int kq = lane >> 4;

    const int er0 = tid >> 2;
    const int er1 = 64 + (tid >> 2);
    const int eko = tid & 3;

    f32x4 acc[4][4];
    #pragma unroll
    for (int a = 0; a < 4; ++a)
        #pragma unroll
        for (int b = 0; b < 4; ++b)
            acc[a][b] = (f32x4){0.f, 0.f, 0.f, 0.f};

    for (int kb = 0; kb < DDIM / 32; ++kb) {
        const int k0 = kb * 32;
        __syncthreads();
        __builtin_amdgcn_global_load_lds(
            (const __attribute__((address_space(1))) void*)(xb + (size_t)(rowbase + er0) * DDIM + k0 + eko * 8),
            (__attribute__((address_space(3))) void*)((char*)Abuf + (wave * 64) * 16),
            16, 0, 0);
        __builtin_amdgcn_global_load_lds(
            (const __attribute__((address_space(1))) void*)(xb + (size_t)(rowbase + er1) * DDIM + k0 + eko * 8),
            (__attribute__((address_space(3))) void*)((char*)Abuf + (256 + wave * 64) * 16),
            16, 0, 0);
        __builtin_amdgcn_global_load_lds(
            (const __attribute__((address_space(1))) void*)(xb + (size_t)(colbase + er0) * DDIM + k0 + eko * 8),
            (__attribute__((address_space(3))) void*)((char*)Bbuf + (wave * 64) * 16),
            16, 0, 0);
        __builtin_amdgcn_global_load_lds(
            (const __attribute__((address_space(1))) void*)(xb + (size_t)(colbase + er1) * DDIM + k0 + eko * 8),
            (__attribute__((address_space(3))) void*)((char*)Bbuf + (256 + wave * 64) * 16),
            16, 0, 0);
        __syncthreads();

        bf16x8 af[4], bfr[4];
        #pragma unroll
        for (int s = 0; s < 4; ++s) {
            af[s]  = *(const bf16x8*)&Abuf[(wr + s * 16 + m16) * 32 + kq * 8];
            bfr[s] = *(const bf16x8*)&Bbuf[(wc + s * 16 + m16) * 32 + kq * 8];
        }
        #pragma unroll
        for (int si = 0; si < 4; ++si)
            #pragma unroll
            for (int sj = 0; sj < 4; ++sj)
                acc[si][sj] = __builtin_amdgcn_mfma_f32_16x16x32_bf16(
                    af[si], bfr[sj], acc[si][sj], 0, 0, 0);
    }

    // ---- pass 1: normal tile ----
    float sqc[4];
    #pragma unroll
    for (int sj = 0; sj < 4; ++sj) sqc[sj] = sq[colbase + wc + sj * 16 + m16];

    #pragma unroll
    for (int si = 0; si < 4; ++si)
        #pragma unroll
        for (int sj = 0; sj < 4; ++sj) {
            int r = wr + si * 16 + kq * 4;
            int c = wc + sj * 16 + m16;
            #pragma unroll
            for (int v = 0; v < 4; ++v)
                Dt[(r + v) * 132 + c] = map16(sqc[sj] - 2.0f * acc[si][sj][v]);
        }
    __syncthreads();

    #pragma unroll
    for (int it = 0; it < 8; ++it) {
        int r = it * 16 + (tid >> 4);
        int ch = tid & 15;
        const unsigned short* p = &Dt[r * 132 + ch * 8];
        union { uint2 q[2]; float4 f; } u;
        u.q[0] = *(const uint2*)p;
        u.q[1] = *(const uint2*)(p + 4);
        *(float4*)&dz[(size_t)(rowbase + r) * NROWS + colbase + ch * 8] = u.f;
    }

    // ---- pass 2: transposed tile (off-diagonal blocks only) ----
    if (bi != bj) {
        __syncthreads();
        #pragma unroll
        for (int si = 0; si < 4; ++si) {
            float4 sqr4 = *(const float4*)&sq[rowbase + wr + si * 16 + kq * 4];
            float sr[4] = {sqr4.x, sqr4.y, sqr4.z, sqr4.w};
            #pragma unroll
            for (int sj = 0; sj < 4; ++sj) {
                int r = wr + si * 16 + kq * 4;
                int c = wc + sj * 16 + m16;
                unsigned short h4[4];
                #pragma unroll
                for (int v = 0; v < 4; ++v)
                    h4[v] = map16(sr[v] - 2.0f * acc[si][sj][v]);
                *(unsigned long long*)&Dt[c * 132 + r] = *(unsigned long long*)h4;
            }
        }
        __syncthreads();
        #pragma unroll
        for (int it = 0; it < 8; ++it) {
            int r = it * 16 + (tid >> 4);
            int ch = tid & 15;
            const unsigned short* p = &Dt[r * 132 + ch * 8];
            union { uint2 q[2]; float4 f; } u;
            u.q[0] = *(const uint2*)p;
            u.q[1] = *(const uint2*)(p + 4);
            *(float4*)&dz[(size_t)(colbase + r) * NROWS + rowbase + ch * 8] = u.f;
        }
    }
}

// ---------------- streaming per-row top-32 screen (1 wave / row) ----------------
// Unique u32 keys: (monotonic u16 << 13) | col. Unsorted 8-slot replace-max
// insert (independent cndmasks, max3 tree) -> no serial bubble chain.
__global__ void __launch_bounds__(256) select_kernel(
    const unsigned short* __restrict__ dz, int* __restrict__ cand)
{
    const int row = blockIdx.x * 4 + (threadIdx.x >> 6);
    const int lane = threadIdx.x & 63;
    const unsigned short* rp = dz + (size_t)row * NROWS + lane * 8;

    // whole row in registers: 16 outstanding 16B loads
    uint4 buf[16];
    #pragma unroll
    for (int p = 0; p < 16; ++p)
        buf[p] = *(const uint4*)(rp + p * 512);

    // distinct sentinels so (slot == m) is always unique
    unsigned int s0 = 0xFFFFFFFFu, s1 = 0xFFFFFFFEu, s2 = 0xFFFFFFFDu, s3 = 0xFFFFFFFCu;
    unsigned int s4 = 0xFFFFFFFBu, s5 = 0xFFFFFFFAu, s6 = 0xFFFFFFF9u, s7 = 0xFFFFFFF8u;
    unsigned int m = 0xFFFFFFFFu;

    #pragma unroll
    for (int p = 0; p < 16; ++p) {
        union { uint4 v; u16x8 h; unsigned short e[8]; } u;
        u.v = buf[p];
        // packed group-min guard (v_pk_min_u16)
        u16x4 g4 = __builtin_elementwise_min(
            __builtin_shufflevector(u.h, u.h, 0, 1, 2, 3),
            __builtin_shufflevector(u.h, u.h, 4, 5, 6, 7));
        u16x2 g2 = __builtin_elementwise_min(
            __builtin_shufflevector(g4, g4, 0, 1),
            __builtin_shufflevector(g4, g4, 2, 3));
        unsigned int gmin = umin_((unsigned int)g2[0], (unsigned int)g2[1]);
        if ((gmin << 13) < m) {
            const int colbase = p * 512 + lane * 8;
            #pragma unroll
            for (int t = 0; t < 8; ++t) {
                unsigned int key = ((unsigned int)u.e[t] << 13) | (unsigned int)(colbase + t);
                if (key < m) {
                    s0 = (s0 == m) ? key : s0;
                    s1 = (s1 == m) ? key : s1;
                    s2 = (s2 == m) ? key : s2;
                    s3 = (s3 == m) ? key : s3;
                    s4 = (s4 == m) ? key : s4;
                    s5 = (s5 == m) ? key : s5;
                    s6 = (s6 == m) ? key : s6;
                    s7 = (s7 == m) ? key : s7;
                    m = umax_(umax_(umax_(s0, s1), umax_(s2, s3)),
                              umax_(umax_(s4, s5), umax_(s6, s7)));
                }
            }
        }
    }

    // wave-wide extraction of top-32 (unsorted output; exact rescore follows)
    unsigned int lmin = umin_(umin_(umin_(s0, s1), umin_(s2, s3)),
                              umin_(umin_(s4, s5), umin_(s6, s7)));
    unsigned int myout = 0;
    for (int t = 0; t < 32; ++t) {
        unsigned int w = lmin;
        #pragma unroll
        for (int off = 32; off > 0; off >>= 1)
            w = umin_(w, (unsigned int)__shfl_xor((int)w, off));
        if (lane == t) myout = w;
        if (lmin == w) {   // unique owner removes the extracted key
            s0 = (s0 == w) ? 0xFFFFFFFFu : s0;
            s1 = (s1 == w) ? 0xFFFFFFFFu : s1;
            s2 = (s2 == w) ? 0xFFFFFFFFu : s2;
            s3 = (s3 == w) ? 0xFFFFFFFFu : s3;
            s4 = (s4 == w) ? 0xFFFFFFFFu : s4;
            s5 = (s5 == w) ? 0xFFFFFFFFu : s5;
            s6 = (s6 == w) ? 0xFFFFFFFFu : s6;
            s7 = (s7 == w) ? 0xFFFFFFFFu : s7;
            lmin = umin_(umin_(umin_(s0, s1), umin_(s2, s3)),
                         umin_(umin_(s4, s5), umin_(s6, s7)));
        }
    }
    if (lane < 32)
        cand[(size_t)row * 32 + lane] = (int)(myout & 8191u);
}

// ---------------- exact fp32 rescore of 32 candidates -> final sorted top-16 ----------------
__global__ void __launch_bounds__(256) rescore_kernel(
    const float* __restrict__ x, const float* __restrict__ sq,
    const int* __restrict__ cand, int* __restrict__ idxOut)
{
    int row = blockIdx.x * 4 + (threadIdx.x >> 6);
    int lane = threadIdx.x & 63;
    float xr[6];
    #pragma unroll
    for (int q = 0; q < 6; ++q) xr[q] = x[(size_t)row * DDIM + lane + 64 * q];
    int myj = cand[(size_t)row * 32 + (lane & 31)];
    float sqrow = sq[row];
    float myd = 0.f;
    for (int c = 0; c < 32; ++c) {
        int j = __shfl(myj, c);
        const float* xc = x + (size_t)j * DDIM;
        float p = 0.f;
        #pragma unroll
        for (int q = 0; q < 6; ++q) p = fmaf(xr[q], xc[lane + 64 * q], p);
        #pragma unroll
        for (int off = 32; off > 0; off >>= 1) p += __shfl_xor(p, off);
        float d = sqrow + sq[j] - 2.f * p;
        if (lane == c) myd = d;
    }
    int rank = 0;
    for (int t = 0; t < 32; ++t) {
        float dt = __shfl(myd, t); int jt = __shfl(myj, t);
        if (dj_better(dt, jt, myd, myj)) ++rank;
    }
    if (lane < 32 && rank < 16) idxOut[(size_t)row * 16 + rank] = myj;
}

// ---------------- gather-mean: agg[row] = mean of first k neighbors' h ----------------
__global__ void __launch_bounds__(256) aggregate_kernel(
    const float* __restrict__ h, const int* __restrict__ idx, const int* __restrict__ kk,
    float* __restrict__ agg)
{
    int row = blockIdx.x, tid = threadIdx.x;
    __shared__ int sidx[16];
    __shared__ int sk;
    if (tid < 16) sidx[tid] = idx[(size_t)row * 16 + tid];
    if (tid == 0) sk = kk[row];
    __syncthreads();
    int k = sk;
    float acc = 0.f;
    for (int t = 0; t < k; ++t) acc += h[(size_t)sidx[t] * HDIM + tid];
    agg[(size_t)row * HDIM + tid] = acc / (float)k;
}

// ---------------- LayerNorm(h + r) * g + b, then @ W_fc + b_fc ----------------
__global__ void __launch_bounds__(256) ln_fc_kernel(
    const float* __restrict__ h, const float* __restrict__ r,
    const float* __restrict__ g, const float* __restrict__ bb,
    const float* __restrict__ W_fc, const float* __restrict__ b_fc,
    float* __restrict__ out)
{
    int row = blockIdx.x, tid = threadIdx.x;
    int wave = tid >> 6, lane = tid & 63;
    float z = h[(size_t)row * HDIM + tid] + r[(size_t)row * HDIM + tid];
    float s = z, s2 = z * z;
    #pragma unroll
    for (int off = 32; off > 0; off >>= 1) { s += __shfl_xor(s, off); s2 += __shfl_xor(s2, off); }
    __shared__ float red[8];
    __shared__ float smv[2];
    if (lane == 0) { red[wave] = s; red[4 + wave] = s2; }
    __syncthreads();
    if (tid == 0) {
        float ts = red[0] + red[1] + red[2] + red[3];
        float t2 = red[4] + red[5] + red[6] + red[7];
        float mu = ts / 256.f;
        float var = t2 / 256.f - mu * mu;
        smv[0] = mu; smv[1] = rsqrtf(var + LN_EPS);
    }
    __syncthreads();
    float zn = (z - smv[0]) * smv[1];
    float val = zn * g[tid] + bb[tid];
    float p[6];
    #pragma unroll
    for (int c = 0; c < 6; ++c) p[c] = val * W_fc[tid * 6 + c];
    #pragma unroll
    for (int c = 0; c < 6; ++c)
        #pragma unroll
        for (int off = 32; off > 0; off >>= 1) p[c] += __shfl_xor(p[c], off);
    __shared__ float pr[4][6];
    if (lane == 0) {
        #pragma unroll
        for (int c = 0; c < 6; ++c) pr[wave][c] = p[c];
    }
    __syncthreads();
    if (tid < 6)
        out[(size_t)row * CDIM + tid] = pr[0][tid] + pr[1][tid] + pr[2][tid] + pr[3][tid] + b_fc[tid];
}

extern "C" void kernel_launch(void* const* d_in, const int* in_sizes, int n_in,
                              void* d_out, int out_size, void* d_ws, size_t ws_size,
                              hipStream_t stream) {
    const float* x      = (const float*)d_in[0];
    const float* W_proj = (const float*)d_in[1];
    const float* b_proj = (const float*)d_in[2];
    const float* W_tau  = (const float*)d_in[3];
    const float* b_tau  = (const float*)d_in[4];
    const float* W_res  = (const float*)d_in[5];
    const float* b_res  = (const float*)d_in[6];
    const float* ln_g   = (const float*)d_in[7];
    const float* ln_b   = (const float*)d_in[8];
    const float* W_fc   = (const float*)d_in[9];
    const float* b_fc   = (const float*)d_in[10];
    float* out = (float*)d_out;

    char* ws = (char*)d_ws;
    float* sq   = (float*)ws;                        ws += (size_t)NROWS * 4;
    int*   kk   = (int*)ws;                          ws += (size_t)NROWS * 4;
    float* h    = (float*)ws;                        ws += (size_t)NROWS * HDIM * 4;
    float* agg  = (float*)ws;                        ws += (size_t)NROWS * HDIM * 4;
    float* r    = (float*)ws;                        ws += (size_t)NROWS * HDIM * 4;
    int*   idx  = (int*)ws;                          ws += (size_t)NROWS * 16 * 4;
    int*   cand = (int*)ws;                          ws += (size_t)NROWS * 32 * 4;
    unsigned short* xb = (unsigned short*)ws;        ws += (size_t)NROWS * DDIM * 2;
    ws = (char*)(((size_t)ws + 255) & ~(size_t)255);
    unsigned short* dz = (unsigned short*)ws;        ws += (size_t)NROWS * NROWS * 2;

    tobf16_kernel<<<NROWS * DDIM / 256, 256, 0, stream>>>(x, xb);
    precompute_kernel<<<NROWS / 4, 256, 0, stream>>>(x, W_tau, b_tau, sq, kk);
    gemm_bias_relu_kernel<<<dim3(NROWS / 64, HDIM / 64), 256, 0, stream>>>(
        x, W_proj, b_proj, h, HDIM, DDIM);
    dist_gemm_kernel<<<(NROWS/128) * (NROWS/128 + 1) / 2, 256, 0, stream>>>(xb, sq, dz);
    select_kernel<<<NROWS / 4, 256, 0, stream>>>(dz, cand);
    rescore_kernel<<<NROWS / 4, 256, 0, stream>>>(x, sq, cand, idx);
    aggregate_kernel<<<NROWS, 256, 0, stream>>>(h, idx, kk, agg);
    gemm_bias_relu_kernel<<<dim3(NROWS / 64, HDIM / 64), 256, 0, stream>>>(
        agg, W_res, b_res, r, HDIM, HDIM);
    ln_fc_kernel<<<NROWS, 256, 0, stream>>>(h, r, ln_g, ln_b, W_fc, b_fc, out);
}

// Round 8
// 303.221 us; speedup vs baseline: 1.3266x; 1.0545x over previous
//
#include <hip/hip_runtime.h>
#include <hip/hip_fp16.h>
#include <math.h>

#define NROWS 8192
#define DDIM 384
#define HDIM 256
#define CDIM 6
#define LN_EPS 1e-5f

typedef short bf16x8 __attribute__((ext_vector_type(8)));
typedef float f32x4 __attribute__((ext_vector_type(4)));
typedef unsigned short u16x8 __attribute__((ext_vector_type(8)));
typedef unsigned short u16x4 __attribute__((ext_vector_type(4)));
typedef unsigned short u16x2 __attribute__((ext_vector_type(2)));

__device__ __forceinline__ bool dj_better(float d1, int j1, float d2, int j2) {
    return (d1 < d2) || (d1 == d2 && j1 < j2);
}

__device__ __forceinline__ unsigned int umin_(unsigned int a, unsigned int b) { return a < b ? a : b; }
__device__ __forceinline__ unsigned int umax_(unsigned int a, unsigned int b) { return a > b ? a : b; }

// fp32 -> fp16 -> monotonic u16 (unsigned order == float order)
__device__ __forceinline__ unsigned short map16(float v) {
    unsigned short b = __half_as_ushort(__float2half(v));
    return (unsigned short)(b ^ (unsigned short)((((short)b) >> 15) | 0x8000));
}

__device__ __forceinline__ unsigned short rne_bf16(float v) {
    unsigned int u = __float_as_uint(v);
    u += 0x7fffu + ((u >> 16) & 1u);
    return (unsigned short)(u >> 16);
}

// ---------------- x (fp32) -> bf16 bits ----------------
__global__ void __launch_bounds__(256) tobf16_kernel(
    const float* __restrict__ x, unsigned short* __restrict__ xb)
{
    int i = blockIdx.x * 256 + threadIdx.x;
    xb[i] = rne_bf16(x[i]);
}

// ---------------- W[k][n] fp32 -> WT[n][k] bf16 ----------------
__global__ void __launch_bounds__(256) transpose_bf16_kernel(
    const float* __restrict__ W, unsigned short* __restrict__ WT, int K, int N)
{
    int i = blockIdx.x * 256 + threadIdx.x;
    if (i >= K * N) return;
    int k = i / N, n = i % N;
    WT[(size_t)n * K + k] = rne_bf16(W[i]);
}

// ---------------- sq[i] = ||x_i||^2, k[i] from tau ----------------
__global__ void __launch_bounds__(256) precompute_kernel(
    const float* __restrict__ x, const float* __restrict__ W_tau,
    const float* __restrict__ b_tau, float* __restrict__ sq, int* __restrict__ kk)
{
    int tid = threadIdx.x;
    int wave = tid >> 6, lane = tid & 63;
    int row = blockIdx.x * 4 + wave;
    const float* xr = x + (size_t)row * DDIM;
    float s = 0.f, tp = 0.f;
    #pragma unroll
    for (int q = 0; q < 6; ++q) {
        float v = xr[lane + 64 * q];
        s = fmaf(v, v, s);
        tp = fmaf(v, W_tau[lane + 64 * q], tp);
    }
    #pragma unroll
    for (int off = 32; off > 0; off >>= 1) {
        s += __shfl_xor(s, off);
        tp += __shfl_xor(tp, off);
    }
    if (lane == 0) {
        sq[row] = s;
        float u = tp + b_tau[0];
        float tau = 1.f / (1.f + expf(-u));
        float kf = rintf(16.f - 12.f * tau);
        int k = (int)kf;
        k = min(16, max(1, k));
        kk[row] = k;
    }
}

// ---------------- MFMA bf16 GEMM: out = relu(A[M,K]@W + bias), W given as WT[n][k] ----------------
// 128x128 tile, 4 waves (2x2), K multiple of 32. Output fp32 [M][256].
__global__ void __launch_bounds__(256) mfma_gemm_bias_relu_kernel(
    const unsigned short* __restrict__ A, const unsigned short* __restrict__ WT,
    const float* __restrict__ bias, float* __restrict__ out, int K)
{
    __shared__ unsigned short Abuf[128 * 32];
    __shared__ unsigned short Bbuf[128 * 32];

    const int tid = threadIdx.x;
    const int wave = tid >> 6;
    const int rowbase = blockIdx.x * 128;
    const int nbase = blockIdx.y * 128;
    const int lane = tid & 63;
    const int wr = (wave >> 1) * 64;
    const int wc = (wave & 1) * 64;
    const int m16 = lane & 15;
    const int kq = lane >> 4;

    const int er0 = tid >> 2;
    const int er1 = 64 + (tid >> 2);
    const int eko = tid & 3;

    f32x4 acc[4][4];
    #pragma unroll
    for (int a = 0; a < 4; ++a)
        #pragma unroll
        for (int b = 0; b < 4; ++b)
            acc[a][b] = (f32x4){0.f, 0.f, 0.f, 0.f};

    for (int kb = 0; kb < K / 32; ++kb) {
        const int k0 = kb * 32;
        __syncthreads();
        __builtin_amdgcn_global_load_lds(
            (const __attribute__((address_space(1))) void*)(A + (size_t)(rowbase + er0) * K + k0 + eko * 8),
            (__attribute__((address_space(3))) void*)((char*)Abuf + (wave * 64) * 16), 16, 0, 0);
        __builtin_amdgcn_global_load_lds(
            (const __attribute__((address_space(1))) void*)(A + (size_t)(rowbase + er1) * K + k0 + eko * 8),
            (__attribute__((address_space(3))) void*)((char*)Abuf + (256 + wave * 64) * 16), 16, 0, 0);
        __builtin_amdgcn_global_load_lds(
            (const __attribute__((address_space(1))) void*)(WT + (size_t)(nbase + er0) * K + k0 + eko * 8),
            (__attribute__((address_space(3))) void*)((char*)Bbuf + (wave * 64) * 16), 16, 0, 0);
        __builtin_amdgcn_global_load_lds(
            (const __attribute__((address_space(1))) void*)(WT + (size_t)(nbase + er1) * K + k0 + eko * 8),
            (__attribute__((address_space(3))) void*)((char*)Bbuf + (256 + wave * 64) * 16), 16, 0, 0);
        __syncthreads();

        bf16x8 af[4], bfr[4];
        #pragma unroll
        for (int s = 0; s < 4; ++s) {
            af[s]  = *(const bf16x8*)&Abuf[(wr + s * 16 + m16) * 32 + kq * 8];
            bfr[s] = *(const bf16x8*)&Bbuf[(wc + s * 16 + m16) * 32 + kq * 8];
        }
        #pragma unroll
        for (int si = 0; si < 4; ++si)
            #pragma unroll
            for (int sj = 0; sj < 4; ++sj)
                acc[si][sj] = __builtin_amdgcn_mfma_f32_16x16x32_bf16(
                    af[si], bfr[sj], acc[si][sj], 0, 0, 0);
    }

    #pragma unroll
    for (int sj = 0; sj < 4; ++sj) {
        int c = nbase + wc + sj * 16 + m16;
        float bc = bias[c];
        #pragma unroll
        for (int si = 0; si < 4; ++si) {
            int r = rowbase + wr + si * 16 + kq * 4;
            #pragma unroll
            for (int v = 0; v < 4; ++v)
                out[(size_t)(r + v) * HDIM + c] = fmaxf(acc[si][sj][v] + bc, 0.f);
        }
    }
}

// ---------------- MFMA bf16 Gram GEMM, symmetric (lower-triangle blocks) ----------------
// dz[i][j] = monotonic-u16( fp16( sq[j] - 2*dot(x_i,x_j) ) )
__global__ void __launch_bounds__(256) dist_gemm_kernel(
    const unsigned short* __restrict__ xb, const float* __restrict__ sq,
    unsigned short* __restrict__ dz)
{
    __shared__ unsigned short Abuf[128 * 32];
    __shared__ unsigned short Bbuf[128 * 32];
    __shared__ __align__(16) unsigned short Dt[128 * 132];

    int t = blockIdx.x;
    int bi = (int)((sqrtf(8.f * (float)t + 1.f) - 1.f) * 0.5f);
    while ((bi + 1) * (bi + 2) / 2 <= t) ++bi;
    while (bi * (bi + 1) / 2 > t) --bi;
    int bj = t - bi * (bi + 1) / 2;

    const int tid = threadIdx.x;
    const int wave = tid >> 6;
    const int lane = tid & 63;
    const int rowbase = bi * 128;
    const int colbase = bj * 128;
    const int wr = (wave >> 1) * 64;
    const int wc = (wave & 1) * 64;
    const int m16 = lane & 15;
    const int kq = lane >> 4;

    const int er0 = tid >> 2;
    const int er1 = 64 + (tid >> 2);
    const int eko = tid & 3;

    f32x4 acc[4][4];
    #pragma unroll
    for (int a = 0; a < 4; ++a)
        #pragma unroll
        for (int b = 0; b < 4; ++b)
            acc[a][b] = (f32x4){0.f, 0.f, 0.f, 0.f};

    for (int kb = 0; kb < DDIM / 32; ++kb) {
        const int k0 = kb * 32;
        __syncthreads();
        __builtin_amdgcn_global_load_lds(
            (const __attribute__((address_space(1))) void*)(xb + (size_t)(rowbase + er0) * DDIM + k0 + eko * 8),
            (__attribute__((address_space(3))) void*)((char*)Abuf + (wave * 64) * 16), 16, 0, 0);
        __builtin_amdgcn_global_load_lds(
            (const __attribute__((address_space(1))) void*)(xb + (size_t)(rowbase + er1) * DDIM + k0 + eko * 8),
            (__attribute__((address_space(3))) void*)((char*)Abuf + (256 + wave * 64) * 16), 16, 0, 0);
        __builtin_amdgcn_global_load_lds(
            (const __attribute__((address_space(1))) void*)(xb + (size_t)(colbase + er0) * DDIM + k0 + eko * 8),
            (__attribute__((address_space(3))) void*)((char*)Bbuf + (wave * 64) * 16), 16, 0, 0);
        __builtin_amdgcn_global_load_lds(
            (const __attribute__((address_space(1))) void*)(xb + (size_t)(colbase + er1) * DDIM + k0 + eko * 8),
            (__attribute__((address_space(3))) void*)((char*)Bbuf + (256 + wave * 64) * 16), 16, 0, 0);
        __syncthreads();

        bf16x8 af[4], bfr[4];
        #pragma unroll
        for (int s = 0; s < 4; ++s) {
            af[s]  = *(const bf16x8*)&Abuf[(wr + s * 16 + m16) * 32 + kq * 8];
            bfr[s] = *(const bf16x8*)&Bbuf[(wc + s * 16 + m16) * 32 + kq * 8];
        }
        #pragma unroll
        for (int si = 0; si < 4; ++si)
            #pragma unroll
            for (int sj = 0; sj < 4; ++sj)
                acc[si][sj] = __builtin_amdgcn_mfma_f32_16x16x32_bf16(
                    af[si], bfr[sj], acc[si][sj], 0, 0, 0);
    }

    // ---- pass 1: normal tile ----
    float sqc[4];
    #pragma unroll
    for (int sj = 0; sj < 4; ++sj) sqc[sj] = sq[colbase + wc + sj * 16 + m16];

    #pragma unroll
    for (int si = 0; si < 4; ++si)
        #pragma unroll
        for (int sj = 0; sj < 4; ++sj) {
            int r = wr + si * 16 + kq * 4;
            int c = wc + sj * 16 + m16;
            #pragma unroll
            for (int v = 0; v < 4; ++v)
                Dt[(r + v) * 132 + c] = map16(sqc[sj] - 2.0f * acc[si][sj][v]);
        }
    __syncthreads();

    #pragma unroll
    for (int it = 0; it < 8; ++it) {
        int r = it * 16 + (tid >> 4);
        int ch = tid & 15;
        const unsigned short* p = &Dt[r * 132 + ch * 8];
        union { uint2 q[2]; float4 f; } u;
        u.q[0] = *(const uint2*)p;
        u.q[1] = *(const uint2*)(p + 4);
        *(float4*)&dz[(size_t)(rowbase + r) * NROWS + colbase + ch * 8] = u.f;
    }

    // ---- pass 2: transposed tile (off-diagonal blocks only) ----
    if (bi != bj) {
        __syncthreads();
        #pragma unroll
        for (int si = 0; si < 4; ++si) {
            float4 sqr4 = *(const float4*)&sq[rowbase + wr + si * 16 + kq * 4];
            float sr[4] = {sqr4.x, sqr4.y, sqr4.z, sqr4.w};
            #pragma unroll
            for (int sj = 0; sj < 4; ++sj) {
                int r = wr + si * 16 + kq * 4;
                int c = wc + sj * 16 + m16;
                unsigned short h4[4];
                #pragma unroll
                for (int v = 0; v < 4; ++v)
                    h4[v] = map16(sr[v] - 2.0f * acc[si][sj][v]);
                *(unsigned long long*)&Dt[c * 132 + r] = *(unsigned long long*)h4;
            }
        }
        __syncthreads();
        #pragma unroll
        for (int it = 0; it < 8; ++it) {
            int r = it * 16 + (tid >> 4);
            int ch = tid & 15;
            const unsigned short* p = &Dt[r * 132 + ch * 8];
            union { uint2 q[2]; float4 f; } u;
            u.q[0] = *(const uint2*)p;
            u.q[1] = *(const uint2*)(p + 4);
            *(float4*)&dz[(size_t)(colbase + r) * NROWS + rowbase + ch * 8] = u.f;
        }
    }
}

// ---------------- streaming per-row top-32 screen (1 wave / row) ----------------
__global__ void __launch_bounds__(256, 1) select_kernel(
    const unsigned short* __restrict__ dz, int* __restrict__ cand)
{
    const int row = blockIdx.x * 4 + (threadIdx.x >> 6);
    const int lane = threadIdx.x & 63;
    const unsigned short* rp = dz + (size_t)row * NROWS + lane * 8;

    // whole row in registers: 16 outstanding 16B loads, pinned above the
    // process loop by a full scheduling barrier (stop the compiler sinking
    // them back to their uses -> real memory-level parallelism).
    uint4 buf[16];
    #pragma unroll
    for (int p = 0; p < 16; ++p)
        buf[p] = *(const uint4*)(rp + p * 512);
    __builtin_amdgcn_sched_barrier(0);

    unsigned int s0 = 0xFFFFFFFFu, s1 = 0xFFFFFFFEu, s2 = 0xFFFFFFFDu, s3 = 0xFFFFFFFCu;
    unsigned int s4 = 0xFFFFFFFBu, s5 = 0xFFFFFFFAu, s6 = 0xFFFFFFF9u, s7 = 0xFFFFFFF8u;
    unsigned int m = 0xFFFFFFFFu;

    #pragma unroll
    for (int p = 0; p < 16; ++p) {
        union { uint4 v; u16x8 h; unsigned short e[8]; } u;
        u.v = buf[p];
        u16x4 g4 = __builtin_elementwise_min(
            __builtin_shufflevector(u.h, u.h, 0, 1, 2, 3),
            __builtin_shufflevector(u.h, u.h, 4, 5, 6, 7));
        u16x2 g2 = __builtin_elementwise_min(
            __builtin_shufflevector(g4, g4, 0, 1),
            __builtin_shufflevector(g4, g4, 2, 3));
        unsigned int gmin = umin_((unsigned int)g2[0], (unsigned int)g2[1]);
        if ((gmin << 13) < m) {
            const int colbase = p * 512 + lane * 8;
            #pragma unroll
            for (int t = 0; t < 8; ++t) {
                unsigned int key = ((unsigned int)u.e[t] << 13) | (unsigned int)(colbase + t);
                if (key < m) {
                    s0 = (s0 == m) ? key : s0;
                    s1 = (s1 == m) ? key : s1;
                    s2 = (s2 == m) ? key : s2;
                    s3 = (s3 == m) ? key : s3;
                    s4 = (s4 == m) ? key : s4;
                    s5 = (s5 == m) ? key : s5;
                    s6 = (s6 == m) ? key : s6;
                    s7 = (s7 == m) ? key : s7;
                    m = umax_(umax_(umax_(s0, s1), umax_(s2, s3)),
                              umax_(umax_(s4, s5), umax_(s6, s7)));
                }
            }
        }
    }

    unsigned int lmin = umin_(umin_(umin_(s0, s1), umin_(s2, s3)),
                              umin_(umin_(s4, s5), umin_(s6, s7)));
    unsigned int myout = 0;
    for (int t = 0; t < 32; ++t) {
        unsigned int w = lmin;
        #pragma unroll
        for (int off = 32; off > 0; off >>= 1)
            w = umin_(w, (unsigned int)__shfl_xor((int)w, off));
        if (lane == t) myout = w;
        if (lmin == w) {
            s0 = (s0 == w) ? 0xFFFFFFFFu : s0;
            s1 = (s1 == w) ? 0xFFFFFFFFu : s1;
            s2 = (s2 == w) ? 0xFFFFFFFFu : s2;
            s3 = (s3 == w) ? 0xFFFFFFFFu : s3;
            s4 = (s4 == w) ? 0xFFFFFFFFu : s4;
            s5 = (s5 == w) ? 0xFFFFFFFFu : s5;
            s6 = (s6 == w) ? 0xFFFFFFFFu : s6;
            s7 = (s7 == w) ? 0xFFFFFFFFu : s7;
            lmin = umin_(umin_(umin_(s0, s1), umin_(s2, s3)),
                         umin_(umin_(s4, s5), umin_(s6, s7)));
        }
    }
    if (lane < 32)
        cand[(size_t)row * 32 + lane] = (int)(myout & 8191u);
}

// ---------------- exact fp32 rescore of 32 candidates -> final sorted top-16 ----------------
__global__ void __launch_bounds__(256) rescore_kernel(
    const float* __restrict__ x, const float* __restrict__ sq,
    const int* __restrict__ cand, int* __restrict__ idxOut)
{
    int row = blockIdx.x * 4 + (threadIdx.x >> 6);
    int lane = threadIdx.x & 63;
    float xr[6];
    #pragma unroll
    for (int q = 0; q < 6; ++q) xr[q] = x[(size_t)row * DDIM + lane + 64 * q];
    int myj = cand[(size_t)row * 32 + (lane & 31)];
    float sqrow = sq[row];
    float myd = 0.f;
    for (int c = 0; c < 32; ++c) {
        int j = __shfl(myj, c);
        const float* xc = x + (size_t)j * DDIM;
        float p = 0.f;
        #pragma unroll
        for (int q = 0; q < 6; ++q) p = fmaf(xr[q], xc[lane + 64 * q], p);
        #pragma unroll
        for (int off = 32; off > 0; off >>= 1) p += __shfl_xor(p, off);
        float d = sqrow + sq[j] - 2.f * p;
        if (lane == c) myd = d;
    }
    int rank = 0;
    for (int t = 0; t < 32; ++t) {
        float dt = __shfl(myd, t); int jt = __shfl(myj, t);
        if (dj_better(dt, jt, myd, myj)) ++rank;
    }
    if (lane < 32 && rank < 16) idxOut[(size_t)row * 16 + rank] = myj;
}

// ---------------- gather-mean -> bf16 agg ----------------
__global__ void __launch_bounds__(256) aggregate_kernel(
    const float* __restrict__ h, const int* __restrict__ idx, const int* __restrict__ kk,
    unsigned short* __restrict__ aggb)
{
    int row = blockIdx.x, tid = threadIdx.x;
    __shared__ int sidx[16];
    __shared__ int sk;
    if (tid < 16) sidx[tid] = idx[(size_t)row * 16 + tid];
    if (tid == 0) sk = kk[row];
    __syncthreads();
    int k = sk;
    float acc = 0.f;
    for (int t = 0; t < k; ++t) acc += h[(size_t)sidx[t] * HDIM + tid];
    aggb[(size_t)row * HDIM + tid] = rne_bf16(acc / (float)k);
}

// ---------------- LayerNorm(h + r) * g + b, then @ W_fc + b_fc ----------------
__global__ void __launch_bounds__(256) ln_fc_kernel(
    const float* __restrict__ h, const float* __restrict__ r,
    const float* __restrict__ g, const float* __restrict__ bb,
    const float* __restrict__ W_fc, const float* __restrict__ b_fc,
    float* __restrict__ out)
{
    int row = blockIdx.x, tid = threadIdx.x;
    int wave = tid >> 6, lane = tid & 63;
    float z = h[(size_t)row * HDIM + tid] + r[(size_t)row * HDIM + tid];
    float s = z, s2 = z * z;
    #pragma unroll
    for (int off = 32; off > 0; off >>= 1) { s += __shfl_xor(s, off); s2 += __shfl_xor(s2, off); }
    __shared__ float red[8];
    __shared__ float smv[2];
    if (lane == 0) { red[wave] = s; red[4 + wave] = s2; }
    __syncthreads();
    if (tid == 0) {
        float ts = red[0] + red[1] + red[2] + red[3];
        float t2 = red[4] + red[5] + red[6] + red[7];
        float mu = ts / 256.f;
        float var = t2 / 256.f - mu * mu;
        smv[0] = mu; smv[1] = rsqrtf(var + LN_EPS);
    }
    __syncthreads();
    float zn = (z - smv[0]) * smv[1];
    float val = zn * g[tid] + bb[tid];
    float p[6];
    #pragma unroll
    for (int c = 0; c < 6; ++c) p[c] = val * W_fc[tid * 6 + c];
    #pragma unroll
    for (int c = 0; c < 6; ++c)
        #pragma unroll
        for (int off = 32; off > 0; off >>= 1) p[c] += __shfl_xor(p[c], off);
    __shared__ float pr[4][6];
    if (lane == 0) {
        #pragma unroll
        for (int c = 0; c < 6; ++c) pr[wave][c] = p[c];
    }
    __syncthreads();
    if (tid < 6)
        out[(size_t)row * CDIM + tid] = pr[0][tid] + pr[1][tid] + pr[2][tid] + pr[3][tid] + b_fc[tid];
}

extern "C" void kernel_launch(void* const* d_in, const int* in_sizes, int n_in,
                              void* d_out, int out_size, void* d_ws, size_t ws_size,
                              hipStream_t stream) {
    const float* x      = (const float*)d_in[0];
    const float* W_proj = (const float*)d_in[1];
    const float* b_proj = (const float*)d_in[2];
    const float* W_tau  = (const float*)d_in[3];
    const float* b_tau  = (const float*)d_in[4];
    const float* W_res  = (const float*)d_in[5];
    const float* b_res  = (const float*)d_in[6];
    const float* ln_g   = (const float*)d_in[7];
    const float* ln_b   = (const float*)d_in[8];
    const float* W_fc   = (const float*)d_in[9];
    const float* b_fc   = (const float*)d_in[10];
    float* out = (float*)d_out;

    char* ws = (char*)d_ws;
    float* sq   = (float*)ws;                        ws += (size_t)NROWS * 4;
    int*   kk   = (int*)ws;                          ws += (size_t)NROWS * 4;
    float* h    = (float*)ws;                        ws += (size_t)NROWS * HDIM * 4;
    float* r    = (float*)ws;                        ws += (size_t)NROWS * HDIM * 4;
    int*   idx  = (int*)ws;                          ws += (size_t)NROWS * 16 * 4;
    int*   cand = (int*)ws;                          ws += (size_t)NROWS * 32 * 4;
    unsigned short* xb   = (unsigned short*)ws;      ws += (size_t)NROWS * DDIM * 2;
    unsigned short* aggb = (unsigned short*)ws;      ws += (size_t)NROWS * HDIM * 2;
    unsigned short* wpT  = (unsigned short*)ws;      ws += (size_t)DDIM * HDIM * 2;
    unsigned short* wrT  = (unsigned short*)ws;      ws += (size_t)HDIM * HDIM * 2;
    ws = (char*)(((size_t)ws + 255) & ~(size_t)255);
    unsigned short* dz = (unsigned short*)ws;        ws += (size_t)NROWS * NROWS * 2;

    tobf16_kernel<<<NROWS * DDIM / 256, 256, 0, stream>>>(x, xb);
    transpose_bf16_kernel<<<(DDIM * HDIM + 255) / 256, 256, 0, stream>>>(W_proj, wpT, DDIM, HDIM);
    transpose_bf16_kernel<<<(HDIM * HDIM + 255) / 256, 256, 0, stream>>>(W_res, wrT, HDIM, HDIM);
    precompute_kernel<<<NROWS / 4, 256, 0, stream>>>(x, W_tau, b_tau, sq, kk);
    mfma_gemm_bias_relu_kernel<<<dim3(NROWS / 128, HDIM / 128), 256, 0, stream>>>(
        xb, wpT, b_proj, h, DDIM);
    dist_gemm_kernel<<<(NROWS/128) * (NROWS/128 + 1) / 2, 256, 0, stream>>>(xb, sq, dz);
    select_kernel<<<NROWS / 4, 256, 0, stream>>>(dz, cand);
    rescore_kernel<<<NROWS / 4, 256, 0, stream>>>(x, sq, cand, idx);
    aggregate_kernel<<<NROWS, 256, 0, stream>>>(h, idx, kk, aggb);
    mfma_gemm_bias_relu_kernel<<<dim3(NROWS / 128, HDIM / 128), 256, 0, stream>>>(
        aggb, wrT, b_res, r, HDIM);
    ln_fc_kernel<<<NROWS, 256, 0, stream>>>(h, r, ln_g, ln_b, W_fc, b_fc, out);
}

// Round 9
// 284.722 us; speedup vs baseline: 1.4128x; 1.0650x over previous
//
#include <hip/hip_runtime.h>
#include <hip/hip_fp16.h>
#include <math.h>

#define NROWS 8192
#define DDIM 384
#define HDIM 256
#define CDIM 6
#define LN_EPS 1e-5f

typedef short bf16x8 __attribute__((ext_vector_type(8)));
typedef float f32x4 __attribute__((ext_vector_type(4)));
typedef unsigned short u16x8 __attribute__((ext_vector_type(8)));
typedef unsigned short u16x4 __attribute__((ext_vector_type(4)));
typedef unsigned short u16x2 __attribute__((ext_vector_type(2)));

__device__ __forceinline__ bool dj_better(float d1, int j1, float d2, int j2) {
    return (d1 < d2) || (d1 == d2 && j1 < j2);
}

__device__ __forceinline__ unsigned int umin_(unsigned int a, unsigned int b) { return a < b ? a : b; }
__device__ __forceinline__ unsigned int umax_(unsigned int a, unsigned int b) { return a > b ? a : b; }

// fp32 -> fp16 -> monotonic u16 (unsigned order == float order)
__device__ __forceinline__ unsigned short map16(float v) {
    unsigned short b = __half_as_ushort(__float2half(v));
    return (unsigned short)(b ^ (unsigned short)((((short)b) >> 15) | 0x8000));
}

__device__ __forceinline__ unsigned short rne_bf16(float v) {
    unsigned int u = __float_as_uint(v);
    u += 0x7fffu + ((u >> 16) & 1u);
    return (unsigned short)(u >> 16);
}

// branchless unsorted 8-slot top-8 insert (replace current max, recompute max)
__device__ __forceinline__ void ins8(
    unsigned int& s0, unsigned int& s1, unsigned int& s2, unsigned int& s3,
    unsigned int& s4, unsigned int& s5, unsigned int& s6, unsigned int& s7,
    unsigned int& m, unsigned int key)
{
    if (key < m) {
        s0 = (s0 == m) ? key : s0;
        s1 = (s1 == m) ? key : s1;
        s2 = (s2 == m) ? key : s2;
        s3 = (s3 == m) ? key : s3;
        s4 = (s4 == m) ? key : s4;
        s5 = (s5 == m) ? key : s5;
        s6 = (s6 == m) ? key : s6;
        s7 = (s7 == m) ? key : s7;
        m = umax_(umax_(umax_(s0, s1), umax_(s2, s3)),
                  umax_(umax_(s4, s5), umax_(s6, s7)));
    }
}

// ---------------- prep: xb = bf16(x), sq[i] = ||x_i||^2, k[i] from tau ----------------
__global__ void __launch_bounds__(256) precompute_kernel(
    const float* __restrict__ x, const float* __restrict__ W_tau,
    const float* __restrict__ b_tau, unsigned short* __restrict__ xb,
    float* __restrict__ sq, int* __restrict__ kk)
{
    int tid = threadIdx.x;
    int wave = tid >> 6, lane = tid & 63;
    int row = blockIdx.x * 4 + wave;
    const float* xr = x + (size_t)row * DDIM;
    unsigned short* xbr = xb + (size_t)row * DDIM;
    float s = 0.f, tp = 0.f;
    #pragma unroll
    for (int q = 0; q < 6; ++q) {
        float v = xr[lane + 64 * q];
        xbr[lane + 64 * q] = rne_bf16(v);
        s = fmaf(v, v, s);
        tp = fmaf(v, W_tau[lane + 64 * q], tp);
    }
    #pragma unroll
    for (int off = 32; off > 0; off >>= 1) {
        s += __shfl_xor(s, off);
        tp += __shfl_xor(tp, off);
    }
    if (lane == 0) {
        sq[row] = s;
        float u = tp + b_tau[0];
        float tau = 1.f / (1.f + expf(-u));
        float kf = rintf(16.f - 12.f * tau);
        int k = (int)kf;
        k = min(16, max(1, k));
        kk[row] = k;
    }
}

// ---------------- both weight transposes (fp32 [K][N] -> bf16 [N][K]) in one launch ----------------
__global__ void __launch_bounds__(256) transpose_bf16_kernel(
    const float* __restrict__ Wp, unsigned short* __restrict__ wpT,
    const float* __restrict__ Wr, unsigned short* __restrict__ wrT)
{
    int i = blockIdx.x * 256 + threadIdx.x;
    if (i < DDIM * HDIM) {
        int k = i / HDIM, n = i % HDIM;
        wpT[(size_t)n * DDIM + k] = rne_bf16(Wp[i]);
    } else {
        int j = i - DDIM * HDIM;
        if (j < HDIM * HDIM) {
            int k = j / HDIM, n = j % HDIM;
            wrT[(size_t)n * HDIM + k] = rne_bf16(Wr[j]);
        }
    }
}

// ---------------- MFMA bf16 GEMM: out = relu(A[M,K]@W + bias), W given as WT[n][k] ----------------
__global__ void __launch_bounds__(256) mfma_gemm_bias_relu_kernel(
    const unsigned short* __restrict__ A, const unsigned short* __restrict__ WT,
    const float* __restrict__ bias, float* __restrict__ out, int K)
{
    __shared__ unsigned short Abuf[128 * 32];
    __shared__ unsigned short Bbuf[128 * 32];

    const int tid = threadIdx.x;
    const int wave = tid >> 6;
    const int rowbase = blockIdx.x * 128;
    const int nbase = blockIdx.y * 128;
    const int lane = tid & 63;
    const int wr = (wave >> 1) * 64;
    const int wc = (wave & 1) * 64;
    const int m16 = lane & 15;
    const int kq = lane >> 4;

    const int er0 = tid >> 2;
    const int er1 = 64 + (tid >> 2);
    const int eko = tid & 3;

    f32x4 acc[4][4];
    #pragma unroll
    for (int a = 0; a < 4; ++a)
        #pragma unroll
        for (int b = 0; b < 4; ++b)
            acc[a][b] = (f32x4){0.f, 0.f, 0.f, 0.f};

    for (int kb = 0; kb < K / 32; ++kb) {
        const int k0 = kb * 32;
        __syncthreads();
        __builtin_amdgcn_global_load_lds(
            (const __attribute__((address_space(1))) void*)(A + (size_t)(rowbase + er0) * K + k0 + eko * 8),
            (__attribute__((address_space(3))) void*)((char*)Abuf + (wave * 64) * 16), 16, 0, 0);
        __builtin_amdgcn_global_load_lds(
            (const __attribute__((address_space(1))) void*)(A + (size_t)(rowbase + er1) * K + k0 + eko * 8),
            (__attribute__((address_space(3))) void*)((char*)Abuf + (256 + wave * 64) * 16), 16, 0, 0);
        __builtin_amdgcn_global_load_lds(
            (const __attribute__((address_space(1))) void*)(WT + (size_t)(nbase + er0) * K + k0 + eko * 8),
            (__attribute__((address_space(3))) void*)((char*)Bbuf + (wave * 64) * 16), 16, 0, 0);
        __builtin_amdgcn_global_load_lds(
            (const __attribute__((address_space(1))) void*)(WT + (size_t)(nbase + er1) * K + k0 + eko * 8),
            (__attribute__((address_space(3))) void*)((char*)Bbuf + (256 + wave * 64) * 16), 16, 0, 0);
        __syncthreads();

        bf16x8 af[4], bfr[4];
        #pragma unroll
        for (int s = 0; s < 4; ++s) {
            af[s]  = *(const bf16x8*)&Abuf[(wr + s * 16 + m16) * 32 + kq * 8];
            bfr[s] = *(const bf16x8*)&Bbuf[(wc + s * 16 + m16) * 32 + kq * 8];
        }
        #pragma unroll
        for (int si = 0; si < 4; ++si)
            #pragma unroll
            for (int sj = 0; sj < 4; ++sj)
                acc[si][sj] = __builtin_amdgcn_mfma_f32_16x16x32_bf16(
                    af[si], bfr[sj], acc[si][sj], 0, 0, 0);
    }

    #pragma unroll
    for (int sj = 0; sj < 4; ++sj) {
        int c = nbase + wc + sj * 16 + m16;
        float bc = bias[c];
        #pragma unroll
        for (int si = 0; si < 4; ++si) {
            int r = rowbase + wr + si * 16 + kq * 4;
            #pragma unroll
            for (int v = 0; v < 4; ++v)
                out[(size_t)(r + v) * HDIM + c] = fmaxf(acc[si][sj][v] + bc, 0.f);
        }
    }
}

// ---------------- MFMA bf16 Gram GEMM + fused per-tile top-8 screening ----------------
// Lower-triangle blocks (bi>=bj). Per 128x128 tile: per row, top-8 keys per
// 64-col half (key = mapped_u16(d') << 13 | col). Off-diagonal blocks also
// produce the transposed tile's keys. keys[row][tile][16].
__global__ void __launch_bounds__(256) dist_topk_kernel(
    const unsigned short* __restrict__ xb, const float* __restrict__ sq,
    unsigned int* __restrict__ keys)
{
    __shared__ unsigned short Abuf[128 * 32];
    __shared__ unsigned short Bbuf[128 * 32];
    __shared__ __align__(16) unsigned short Dt[128 * 136];   // 34 KB, 16B-aligned rows

    int t = blockIdx.x;
    int bi = (int)((sqrtf(8.f * (float)t + 1.f) - 1.f) * 0.5f);
    while ((bi + 1) * (bi + 2) / 2 <= t) ++bi;
    while (bi * (bi + 1) / 2 > t) --bi;
    int bj = t - bi * (bi + 1) / 2;

    const int tid = threadIdx.x;
    const int wave = tid >> 6;
    const int lane = tid & 63;
    const int rowbase = bi * 128;
    const int colbase = bj * 128;
    const int wr = (wave >> 1) * 64;
    const int wc = (wave & 1) * 64;
    const int m16 = lane & 15;
    const int kq = lane >> 4;

    const int er0 = tid >> 2;
    const int er1 = 64 + (tid >> 2);
    const int eko = tid & 3;

    f32x4 acc[4][4];
    #pragma unroll
    for (int a = 0; a < 4; ++a)
        #pragma unroll
        for (int b = 0; b < 4; ++b)
            acc[a][b] = (f32x4){0.f, 0.f, 0.f, 0.f};

    for (int kb = 0; kb < DDIM / 32; ++kb) {
        const int k0 = kb * 32;
        __syncthreads();
        __builtin_amdgcn_global_load_lds(
            (const __attribute__((address_space(1))) void*)(xb + (size_t)(rowbase + er0) * DDIM + k0 + eko * 8),
            (__attribute__((address_space(3))) void*)((char*)Abuf + (wave * 64) * 16), 16, 0, 0);
        __builtin_amdgcn_global_load_lds(
            (const __attribute__((address_space(1))) void*)(xb + (size_t)(rowbase + er1) * DDIM + k0 + eko * 8),
            (__attribute__((address_space(3))) void*)((char*)Abuf + (256 + wave * 64) * 16), 16, 0, 0);
        __builtin_amdgcn_global_load_lds(
            (const __attribute__((address_space(1))) void*)(xb + (size_t)(colbase + er0) * DDIM + k0 + eko * 8),
            (__attribute__((address_space(3))) void*)((char*)Bbuf + (wave * 64) * 16), 16, 0, 0);
        __builtin_amdgcn_global_load_lds(
            (const __attribute__((address_space(1))) void*)(xb + (size_t)(colbase + er1) * DDIM + k0 + eko * 8),
            (__attribute__((address_space(3))) void*)((char*)Bbuf + (256 + wave * 64) * 16), 16, 0, 0);
        __syncthreads();

        bf16x8 af[4], bfr[4];
        #pragma unroll
        for (int s = 0; s < 4; ++s) {
            af[s]  = *(const bf16x8*)&Abuf[(wr + s * 16 + m16) * 32 + kq * 8];
            bfr[s] = *(const bf16x8*)&Bbuf[(wc + s * 16 + m16) * 32 + kq * 8];
        }
        #pragma unroll
        for (int si = 0; si < 4; ++si)
            #pragma unroll
            for (int sj = 0; sj < 4; ++sj)
                acc[si][sj] = __builtin_amdgcn_mfma_f32_16x16x32_bf16(
                    af[si], bfr[sj], acc[si][sj], 0, 0, 0);
    }

    const int sr = tid >> 1;          // scan row in tile
    const int seg = tid & 1;          // 64-col half

    // ==== pass 1: rows of bi-block, tile bj ====
    {
        float sqc[4];
        #pragma unroll
        for (int sj = 0; sj < 4; ++sj) sqc[sj] = sq[colbase + wc + sj * 16 + m16];
        #pragma unroll
        for (int si = 0; si < 4; ++si)
            #pragma unroll
            for (int sj = 0; sj < 4; ++sj) {
                int r = wr + si * 16 + kq * 4;
                int c = wc + sj * 16 + m16;
                #pragma unroll
                for (int v = 0; v < 4; ++v)
                    Dt[(r + v) * 136 + c] = map16(sqc[sj] - 2.0f * acc[si][sj][v]);
            }
        __syncthreads();

        unsigned int s0 = 0xFFFFFFFFu, s1 = 0xFFFFFFFEu, s2 = 0xFFFFFFFDu, s3 = 0xFFFFFFFCu;
        unsigned int s4 = 0xFFFFFFFBu, s5 = 0xFFFFFFFAu, s6 = 0xFFFFFFF9u, s7 = 0xFFFFFFF8u;
        unsigned int m = 0xFFFFFFFFu;
        const unsigned short* rowp = &Dt[sr * 136 + seg * 64];
        #pragma unroll
        for (int i = 0; i < 8; ++i) {
            u16x8 ch = *(const u16x8*)(rowp + i * 8);
            u16x4 g4 = __builtin_elementwise_min(
                __builtin_shufflevector(ch, ch, 0, 1, 2, 3),
                __builtin_shufflevector(ch, ch, 4, 5, 6, 7));
            u16x2 g2 = __builtin_elementwise_min(
                __builtin_shufflevector(g4, g4, 0, 1),
                __builtin_shufflevector(g4, g4, 2, 3));
            unsigned int gmin = umin_((unsigned int)g2[0], (unsigned int)g2[1]);
            if ((gmin << 13) < m) {
                int cb = colbase + seg * 64 + i * 8;
                #pragma unroll
                for (int e = 0; e < 8; ++e)
                    ins8(s0, s1, s2, s3, s4, s5, s6, s7, m,
                         ((unsigned int)ch[e] << 13) | (unsigned int)(cb + e));
            }
        }
        size_t kb = (size_t)(rowbase + sr) * 1024 + (size_t)bj * 16 + seg * 8;
        uint4 o0; o0.x = s0; o0.y = s1; o0.z = s2; o0.w = s3;
        uint4 o1; o1.x = s4; o1.y = s5; o1.z = s6; o1.w = s7;
        *(uint4*)&keys[kb] = o0;
        *(uint4*)&keys[kb + 4] = o1;
    }

    // ==== pass 2: rows of bj-block, tile bi (off-diagonal only) ====
    if (bi != bj) {
        __syncthreads();   // pass-1 scans done before overwriting Dt
        #pragma unroll
        for (int si = 0; si < 4; ++si) {
            float4 sqr4 = *(const float4*)&sq[rowbase + wr + si * 16 + kq * 4];
            float srw[4] = {sqr4.x, sqr4.y, sqr4.z, sqr4.w};
            #pragma unroll
            for (int sj = 0; sj < 4; ++sj) {
                int r = wr + si * 16 + kq * 4;
                int c = wc + sj * 16 + m16;
                unsigned short h4[4];
                #pragma unroll
                for (int v = 0; v < 4; ++v)
                    h4[v] = map16(srw[v] - 2.0f * acc[si][sj][v]);
                *(unsigned long long*)&Dt[c * 136 + r] = *(unsigned long long*)h4;
            }
        }
        __syncthreads();

        unsigned int s0 = 0xFFFFFFFFu, s1 = 0xFFFFFFFEu, s2 = 0xFFFFFFFDu, s3 = 0xFFFFFFFCu;
        unsigned int s4 = 0xFFFFFFFBu, s5 = 0xFFFFFFFAu, s6 = 0xFFFFFFF9u, s7 = 0xFFFFFFF8u;
        unsigned int m = 0xFFFFFFFFu;
        const unsigned short* rowp = &Dt[sr * 136 + seg * 64];
        #pragma unroll
        for (int i = 0; i < 8; ++i) {
            u16x8 ch = *(const u16x8*)(rowp + i * 8);
            u16x4 g4 = __builtin_elementwise_min(
                __builtin_shufflevector(ch, ch, 0, 1, 2, 3),
                __builtin_shufflevector(ch, ch, 4, 5, 6, 7));
            u16x2 g2 = __builtin_elementwise_min(
                __builtin_shufflevector(g4, g4, 0, 1),
                __builtin_shufflevector(g4, g4, 2, 3));
            unsigned int gmin = umin_((unsigned int)g2[0], (unsigned int)g2[1]);
            if ((gmin << 13) < m) {
                int cb = rowbase + seg * 64 + i * 8;
                #pragma unroll
                for (int e = 0; e < 8; ++e)
                    ins8(s0, s1, s2, s3, s4, s5, s6, s7, m,
                         ((unsigned int)ch[e] << 13) | (unsigned int)(cb + e));
            }
        }
        size_t kb = (size_t)(colbase + sr) * 1024 + (size_t)bi * 16 + seg * 8;
        uint4 o0; o0.x = s0; o0.y = s1; o0.z = s2; o0.w = s3;
        uint4 o1; o1.x = s4; o1.y = s5; o1.z = s6; o1.w = s7;
        *(uint4*)&keys[kb] = o0;
        *(uint4*)&keys[kb + 4] = o1;
    }
}

// ---------------- merge per-tile keys -> top-32 candidates (1 wave / row) ----------------
__global__ void __launch_bounds__(256) select_merge_kernel(
    const unsigned int* __restrict__ keys, int* __restrict__ cand)
{
    const int row = blockIdx.x * 4 + (threadIdx.x >> 6);
    const int lane = threadIdx.x & 63;
    const uint4* kp = (const uint4*)(keys + (size_t)row * 1024 + lane * 16);

    unsigned int s0 = 0xFFFFFFFFu, s1 = 0xFFFFFFFEu, s2 = 0xFFFFFFFDu, s3 = 0xFFFFFFFCu;
    unsigned int s4 = 0xFFFFFFFBu, s5 = 0xFFFFFFFAu, s6 = 0xFFFFFFF9u, s7 = 0xFFFFFFF8u;
    unsigned int m = 0xFFFFFFFFu;

    #pragma unroll
    for (int q = 0; q < 4; ++q) {
        uint4 v = kp[q];
        unsigned int gmin = umin_(umin_(v.x, v.y), umin_(v.z, v.w));
        if (gmin < m) {
            ins8(s0, s1, s2, s3, s4, s5, s6, s7, m, v.x);
            ins8(s0, s1, s2, s3, s4, s5, s6, s7, m, v.y);
            ins8(s0, s1, s2, s3, s4, s5, s6, s7, m, v.z);
            ins8(s0, s1, s2, s3, s4, s5, s6, s7, m, v.w);
        }
    }

    unsigned int lmin = umin_(umin_(umin_(s0, s1), umin_(s2, s3)),
                              umin_(umin_(s4, s5), umin_(s6, s7)));
    unsigned int myout = 0;
    for (int t = 0; t < 32; ++t) {
        unsigned int w = lmin;
        #pragma unroll
        for (int off = 32; off > 0; off >>= 1)
            w = umin_(w, (unsigned int)__shfl_xor((int)w, off));
        if (lane == t) myout = w;
        if (lmin == w) {
            s0 = (s0 == w) ? 0xFFFFFFFFu : s0;
            s1 = (s1 == w) ? 0xFFFFFFFFu : s1;
            s2 = (s2 == w) ? 0xFFFFFFFFu : s2;
            s3 = (s3 == w) ? 0xFFFFFFFFu : s3;
            s4 = (s4 == w) ? 0xFFFFFFFFu : s4;
            s5 = (s5 == w) ? 0xFFFFFFFFu : s5;
            s6 = (s6 == w) ? 0xFFFFFFFFu : s6;
            s7 = (s7 == w) ? 0xFFFFFFFFu : s7;
            lmin = umin_(umin_(umin_(s0, s1), umin_(s2, s3)),
                         umin_(umin_(s4, s5), umin_(s6, s7)));
        }
    }
    if (lane < 32)
        cand[(size_t)row * 32 + lane] = (int)(myout & 8191u);
}

// ---------------- exact fp32 rescore of 32 candidates -> final sorted top-16 ----------------
__global__ void __launch_bounds__(256) rescore_kernel(
    const float* __restrict__ x, const float* __restrict__ sq,
    const int* __restrict__ cand, int* __restrict__ idxOut)
{
    int row = blockIdx.x * 4 + (threadIdx.x >> 6);
    int lane = threadIdx.x & 63;
    float xr[6];
    #pragma unroll
    for (int q = 0; q < 6; ++q) xr[q] = x[(size_t)row * DDIM + lane + 64 * q];
    int myj = cand[(size_t)row * 32 + (lane & 31)];
    float sqrow = sq[row];
    float myd = 0.f;
    for (int c = 0; c < 32; ++c) {
        int j = __shfl(myj, c);
        const float* xc = x + (size_t)j * DDIM;
        float p = 0.f;
        #pragma unroll
        for (int q = 0; q < 6; ++q) p = fmaf(xr[q], xc[lane + 64 * q], p);
        #pragma unroll
        for (int off = 32; off > 0; off >>= 1) p += __shfl_xor(p, off);
        float d = sqrow + sq[j] - 2.f * p;
        if (lane == c) myd = d;
    }
    int rank = 0;
    for (int t = 0; t < 32; ++t) {
        float dt = __shfl(myd, t); int jt = __shfl(myj, t);
        if (dj_better(dt, jt, myd, myj)) ++rank;
    }
    if (lane < 32 && rank < 16) idxOut[(size_t)row * 16 + rank] = myj;
}

// ---------------- gather-mean -> bf16 agg ----------------
__global__ void __launch_bounds__(256) aggregate_kernel(
    const float* __restrict__ h, const int* __restrict__ idx, const int* __restrict__ kk,
    unsigned short* __restrict__ aggb)
{
    int row = blockIdx.x, tid = threadIdx.x;
    __shared__ int sidx[16];
    __shared__ int sk;
    if (tid < 16) sidx[tid] = idx[(size_t)row * 16 + tid];
    if (tid == 0) sk = kk[row];
    __syncthreads();
    int k = sk;
    float acc = 0.f;
    for (int t = 0; t < k; ++t) acc += h[(size_t)sidx[t] * HDIM + tid];
    aggb[(size_t)row * HDIM + tid] = rne_bf16(acc / (float)k);
}

// ---------------- LayerNorm(h + r) * g + b, then @ W_fc + b_fc ----------------
__global__ void __launch_bounds__(256) ln_fc_kernel(
    const float* __restrict__ h, const float* __restrict__ r,
    const float* __restrict__ g, const float* __restrict__ bb,
    const float* __restrict__ W_fc, const float* __restrict__ b_fc,
    float* __restrict__ out)
{
    int row = blockIdx.x, tid = threadIdx.x;
    int wave = tid >> 6, lane = tid & 63;
    float z = h[(size_t)row * HDIM + tid] + r[(size_t)row * HDIM + tid];
    float s = z, s2 = z * z;
    #pragma unroll
    for (int off = 32; off > 0; off >>= 1) { s += __shfl_xor(s, off); s2 += __shfl_xor(s2, off); }
    __shared__ float red[8];
    __shared__ float smv[2];
    if (lane == 0) { red[wave] = s; red[4 + wave] = s2; }
    __syncthreads();
    if (tid == 0) {
        float ts = red[0] + red[1] + red[2] + red[3];
        float t2 = red[4] + red[5] + red[6] + red[7];
        float mu = ts / 256.f;
        float var = t2 / 256.f - mu * mu;
        smv[0] = mu; smv[1] = rsqrtf(var + LN_EPS);
    }
    __syncthreads();
    float zn = (z - smv[0]) * smv[1];
    float val = zn * g[tid] + bb[tid];
    float p[6];
    #pragma unroll
    for (int c = 0; c < 6; ++c) p[c] = val * W_fc[tid * 6 + c];
    #pragma unroll
    for (int c = 0; c < 6; ++c)
        #pragma unroll
        for (int off = 32; off > 0; off >>= 1) p[c] += __shfl_xor(p[c], off);
    __shared__ float pr[4][6];
    if (lane == 0) {
        #pragma unroll
        for (int c = 0; c < 6; ++c) pr[wave][c] = p[c];
    }
    __syncthreads();
    if (tid < 6)
        out[(size_t)row * CDIM + tid] = pr[0][tid] + pr[1][tid] + pr[2][tid] + pr[3][tid] + b_fc[tid];
}

extern "C" void kernel_launch(void* const* d_in, const int* in_sizes, int n_in,
                              void* d_out, int out_size, void* d_ws, size_t ws_size,
                              hipStream_t stream) {
    const float* x      = (const float*)d_in[0];
    const float* W_proj = (const float*)d_in[1];
    const float* b_proj = (const float*)d_in[2];
    const float* W_tau  = (const float*)d_in[3];
    const float* b_tau  = (const float*)d_in[4];
    const float* W_res  = (const float*)d_in[5];
    const float* b_res  = (const float*)d_in[6];
    const float* ln_g   = (const float*)d_in[7];
    const float* ln_b   = (const float*)d_in[8];
    const float* W_fc   = (const float*)d_in[9];
    const float* b_fc   = (const float*)d_in[10];
    float* out = (float*)d_out;

    char* ws = (char*)d_ws;
    float* sq   = (float*)ws;                        ws += (size_t)NROWS * 4;
    int*   kk   = (int*)ws;                          ws += (size_t)NROWS * 4;
    float* h    = (float*)ws;                        ws += (size_t)NROWS * HDIM * 4;
    float* r    = (float*)ws;                        ws += (size_t)NROWS * HDIM * 4;
    int*   idx  = (int*)ws;                          ws += (size_t)NROWS * 16 * 4;
    int*   cand = (int*)ws;                          ws += (size_t)NROWS * 32 * 4;
    unsigned short* xb   = (unsigned short*)ws;      ws += (size_t)NROWS * DDIM * 2;
    unsigned short* aggb = (unsigned short*)ws;      ws += (size_t)NROWS * HDIM * 2;
    unsigned short* wpT  = (unsigned short*)ws;      ws += (size_t)DDIM * HDIM * 2;
    unsigned short* wrT  = (unsigned short*)ws;      ws += (size_t)HDIM * HDIM * 2;
    ws = (char*)(((size_t)ws + 255) & ~(size_t)255);
    unsigned int* keys = (unsigned int*)ws;          ws += (size_t)NROWS * 1024 * 4;   // 32 MB

    precompute_kernel<<<NROWS / 4, 256, 0, stream>>>(x, W_tau, b_tau, xb, sq, kk);
    transpose_bf16_kernel<<<(DDIM * HDIM + HDIM * HDIM + 255) / 256, 256, 0, stream>>>(
        W_proj, wpT, W_res, wrT);
    mfma_gemm_bias_relu_kernel<<<dim3(NROWS / 128, HDIM / 128), 256, 0, stream>>>(
        xb, wpT, b_proj, h, DDIM);
    dist_topk_kernel<<<(NROWS/128) * (NROWS/128 + 1) / 2, 256, 0, stream>>>(xb, sq, keys);
    select_merge_kernel<<<NROWS / 4, 256, 0, stream>>>(keys, cand);
    rescore_kernel<<<NROWS / 4, 256, 0, stream>>>(x, sq, cand, idx);
    aggregate_kernel<<<NROWS, 256, 0, stream>>>(h, idx, kk, aggb);
    mfma_gemm_bias_relu_kernel<<<dim3(NROWS / 128, HDIM / 128), 256, 0, stream>>>(
        aggb, wrT, b_res, r, HDIM);
    ln_fc_kernel<<<NROWS, 256, 0, stream>>>(h, r, ln_g, ln_b, W_fc, b_fc, out);
}